// Round 8
// baseline (1978.520 us; speedup 1.0000x reference)
//
#include <hip/hip_runtime.h>

#define BB 4
#define NN 4096
#define KK 40

#define NEG_FLT (-3.402823466e38f)
#define POS_FLT (3.402823466e38f)

typedef __attribute__((ext_vector_type(8))) short short8;
typedef __attribute__((ext_vector_type(4))) float f32x4;

__device__ __forceinline__ float lrelu02(float v){ return v > 0.f ? v : 0.2f*v; }
__device__ __forceinline__ int f2ord(float f){ int u = __float_as_int(f); return u >= 0 ? u : (u ^ 0x7fffffff); }
__device__ __forceinline__ unsigned ordu(float f){
  unsigned u = __float_as_uint(f);
  return (u & 0x80000000u) ? ~u : (u | 0x80000000u);
}
__device__ __forceinline__ unsigned long long packkey(float v, int m){
  return ((unsigned long long)ordu(v) << 32) | (unsigned)(~m);
}
__device__ __forceinline__ unsigned short f2bf(float f){   // RNE f32->bf16
  unsigned u = __float_as_uint(f);
  unsigned r = u + 0x7fffu + ((u>>16)&1u);
  return (unsigned short)(r>>16);
}

// ---------------- xx = sum_c x^2 ----------------
template<int C>
__global__ void xx_kernel(const float* __restrict__ x, float* __restrict__ xx){
  int i = blockIdx.x*blockDim.x + threadIdx.x;
  if(i >= BB*NN) return;
  int b = i / NN, n = i % NN;
  const float* xb = x + (size_t)b*C*NN + n;
  float s = 0.f;
  #pragma unroll
  for(int c=0;c<C;c++){ float v = xb[(size_t)c*NN]; s += v*v; }
  xx[i] = s;
}

// ---------------- distance matrix: 128x128 fp32 tile, K-step 16, SYMMETRIC ----------------
// only tiles with m0 >= n0 are computed; the transposed tile is mirror-written.
// per-(n,m) accumulation is a single fmac chain over ascending c -> bit-identical
// in both copies -> identical kNN ordering.
template<int C>
__global__ __launch_bounds__(256)
void dist_kernel(const float* __restrict__ xb, const float* __restrict__ xx,
                 float* __restrict__ dist){
  const int n0 = blockIdx.y*128, m0 = blockIdx.x*128;
  if(m0 < n0) return;
  __shared__ float As[16][132];
  __shared__ float Bs[16][132];
  const int tid = threadIdx.x;
  const int tx = tid & 15, ty = tid >> 4;
  const int lr = tid >> 4;           // staging k-row 0..15
  const int lc0 = (tid & 15)*8;      // staging col base
  float acc[8][8] = {};
  for(int kt=0; kt<C; kt+=16){
    __syncthreads();
    {
      const float* an = xb + (size_t)(kt+lr)*NN + n0 + lc0;
      const float* am = xb + (size_t)(kt+lr)*NN + m0 + lc0;
      *(float4*)&As[lr][lc0]   = *(const float4*)an;
      *(float4*)&As[lr][lc0+4] = *(const float4*)(an+4);
      *(float4*)&Bs[lr][lc0]   = *(const float4*)am;
      *(float4*)&Bs[lr][lc0+4] = *(const float4*)(am+4);
    }
    __syncthreads();
    #pragma unroll
    for(int cc=0;cc<16;cc++){
      float a[8], b[8];
      *(float4*)&a[0] = *(const float4*)&As[cc][ty*8];
      *(float4*)&a[4] = *(const float4*)&As[cc][ty*8+4];
      *(float4*)&b[0] = *(const float4*)&Bs[cc][tx*8];
      *(float4*)&b[4] = *(const float4*)&Bs[cc][tx*8+4];
      #pragma unroll
      for(int i=0;i<8;i++)
        #pragma unroll
        for(int j=0;j<8;j++) acc[i][j] += a[i]*b[j];
    }
  }
  float xmv[8], xnv[8];
  #pragma unroll
  for(int j=0;j<8;j++) xmv[j] = xx[m0 + tx*8 + j];
  #pragma unroll
  for(int i=0;i<8;i++) xnv[i] = xx[n0 + ty*8 + i];
  // normal (n,m) write — coalesced
  #pragma unroll
  for(int i=0;i<8;i++){
    int n = n0 + ty*8 + i;
    float xn = xnv[i];
    float4 r0, r1;
    r0.x = 2.f*acc[i][0] - xn - xmv[0];
    r0.y = 2.f*acc[i][1] - xn - xmv[1];
    r0.z = 2.f*acc[i][2] - xn - xmv[2];
    r0.w = 2.f*acc[i][3] - xn - xmv[3];
    r1.x = 2.f*acc[i][4] - xn - xmv[4];
    r1.y = 2.f*acc[i][5] - xn - xmv[5];
    r1.z = 2.f*acc[i][6] - xn - xmv[6];
    r1.w = 2.f*acc[i][7] - xn - xmv[7];
    *(float4*)(dist + (size_t)n*NN + m0 + tx*8)     = r0;
    *(float4*)(dist + (size_t)n*NN + m0 + tx*8 + 4) = r1;
  }
  // mirrored (m,n) write — off-diagonal tiles only; 32B contiguous per store
  if(m0 != n0){
    #pragma unroll
    for(int j=0;j<8;j++){
      int m = m0 + tx*8 + j;
      float xm = xmv[j];
      float4 r0, r1;
      r0.x = 2.f*acc[0][j] - xnv[0] - xm;
      r0.y = 2.f*acc[1][j] - xnv[1] - xm;
      r0.z = 2.f*acc[2][j] - xnv[2] - xm;
      r0.w = 2.f*acc[3][j] - xnv[3] - xm;
      r1.x = 2.f*acc[4][j] - xnv[4] - xm;
      r1.y = 2.f*acc[5][j] - xnv[5] - xm;
      r1.z = 2.f*acc[6][j] - xnv[6] - xm;
      r1.w = 2.f*acc[7][j] - xnv[7] - xm;
      *(float4*)(dist + (size_t)m*NN + n0 + ty*8)     = r0;
      *(float4*)(dist + (size_t)m*NN + n0 + ty*8 + 4) = r1;
    }
  }
}

// C=3 direct distance kernel
__global__ __launch_bounds__(256)
void dist3_kernel(const float* __restrict__ xb, const float* __restrict__ xx,
                  float* __restrict__ dist){
  int n = blockIdx.y;
  int m0 = (blockIdx.x*256 + threadIdx.x)*4;
  float c0 = xb[n], c1 = xb[NN+n], c2 = xb[2*NN+n];
  float xn = xx[n];
  float4 a = *(const float4*)(xb + m0);
  float4 b = *(const float4*)(xb + NN + m0);
  float4 c = *(const float4*)(xb + 2*NN + m0);
  float4 xm = *(const float4*)(xx + m0);
  float4 r;
  { float s = c0*a.x; s += c1*b.x; s += c2*c.x; r.x = 2.f*s - xn - xm.x; }
  { float s = c0*a.y; s += c1*b.y; s += c2*c.y; r.y = 2.f*s - xn - xm.y; }
  { float s = c0*a.z; s += c1*b.z; s += c2*c.z; r.z = 2.f*s - xn - xm.z; }
  { float s = c0*a.w; s += c1*b.w; s += c2*c.w; r.w = 2.f*s - xn - xm.w; }
  *(float4*)(dist + (size_t)n*NN + m0) = r;
}

// branch-free sorted-insert ladder on NAMED registers (no refs -> no scratch)
#define INSQ(vf, mi) do{ \
  unsigned long long _pk = packkey((vf),(mi)); \
  if(_pk > t7){ \
    unsigned long long _lo; \
    _lo = _pk < t0 ? _pk : t0;  t0 = _pk > t0 ? _pk : t0;  _pk = _lo; \
    _lo = _pk < t1 ? _pk : t1;  t1 = _pk > t1 ? _pk : t1;  _pk = _lo; \
    _lo = _pk < t2 ? _pk : t2;  t2 = _pk > t2 ? _pk : t2;  _pk = _lo; \
    _lo = _pk < t3 ? _pk : t3;  t3 = _pk > t3 ? _pk : t3;  _pk = _lo; \
    _lo = _pk < t4 ? _pk : t4;  t4 = _pk > t4 ? _pk : t4;  _pk = _lo; \
    _lo = _pk < t5 ? _pk : t5;  t5 = _pk > t5 ? _pk : t5;  _pk = _lo; \
    _lo = _pk < t6 ? _pk : t6;  t6 = _pk > t6 ? _pk : t6;  _pk = _lo; \
    t7 = _pk > t7 ? _pk : t7; \
  } \
}while(0)

// ---------------- top-K: 4 rows/block (4 waves), rows split across two dist buffers ----------------
__global__ __launch_bounds__(256)
void select_kernel(const float* __restrict__ dA, const float* __restrict__ dB,
                   int* __restrict__ idx){
  const int wid = threadIdx.x >> 6;
  const int lane = threadIdx.x & 63;
  const int r = blockIdx.x*4 + wid;            // 0..8191 (two batches)
  const float* row = (r < NN) ? (dA + (size_t)r*NN) : (dB + (size_t)(r-NN)*NN);

  unsigned long long t0=0,t1=0,t2=0,t3=0,t4=0,t5=0,t6=0,t7=0;
  unsigned long long done = 0ull;

  #pragma unroll 4
  for(int j=0;j<16;j++){
    float4 v = *(const float4*)(row + j*256 + lane*4);
    int mb = j*256 + lane*4;
    INSQ(v.x, mb+0); INSQ(v.y, mb+1); INSQ(v.z, mb+2); INSQ(v.w, mb+3);
  }

  __shared__ int outbuf[4][KK];
  #pragma unroll 1
  for(int k=0;k<KK;k++){
    unsigned long long wv = t0;
    #pragma unroll
    for(int off=32; off; off>>=1){
      unsigned long long ov = __shfl_xor(wv, off, 64);
      wv = ov > wv ? ov : wv;
    }
    int m = (int)(~(unsigned)wv);
    if(lane == ((m>>2)&63)){
      done |= 1ull << (((m>>8)<<2) | (m&3));
      t0=t1;t1=t2;t2=t3;t3=t4;t4=t5;t5=t6;t6=t7;t7=0;
      if(t0 == 0ull){
        // rare rebuild from the cached row, skipping extracted
        #pragma unroll 1
        for(int j=0;j<16;j++){
          float4 v = *(const float4*)(row + j*256 + lane*4);
          int mb = j*256 + lane*4;
          if(!((done>>(j*4+0))&1)) INSQ(v.x, mb+0);
          if(!((done>>(j*4+1))&1)) INSQ(v.y, mb+1);
          if(!((done>>(j*4+2))&1)) INSQ(v.z, mb+2);
          if(!((done>>(j*4+3))&1)) INSQ(v.w, mb+3);
        }
      }
    }
    if(lane == 0) outbuf[wid][k] = m;
  }
  if(lane < KK) idx[(size_t)r*KK + lane] = outbuf[wid][lane];
}

// ---------------- W transpose + delta: Wt1[c][o]=w1, Wtd[c][o]=w2-w1 ----------------
template<int C, int O>
__global__ void wt_kernel(const float* __restrict__ w, float* __restrict__ Wt1,
                          float* __restrict__ Wtd){
  int i = blockIdx.x*256 + threadIdx.x;
  if(i >= C*O) return;
  int c = i / O, o = i % O;
  float a = w[(size_t)o*2*C + c];
  float b = w[(size_t)o*2*C + C + c];
  Wt1[i] = a; Wtd[i] = b - a;
}

// ---------------- pq as dual-output fp32 GEMM: 64x64 tile, K-step 32 ----------------
template<int C, int O>
__global__ __launch_bounds__(256)
void pq_gemm_kernel(const float* __restrict__ x, const float* __restrict__ Wt1,
                    const float* __restrict__ Wtd, const float* __restrict__ bias,
                    float* __restrict__ P, float* __restrict__ Q){
  __shared__ float Xs[32][68];
  __shared__ float W1s[32][68];
  __shared__ float Wds[32][68];
  const int t0 = blockIdx.x*64;
  const int o0 = blockIdx.y*64;
  const int b  = t0 / NN, n0 = t0 % NN;   // NN%64==0 -> tile within one batch
  const float* xb = x + (size_t)b*C*NN;
  const int tid = threadIdx.x;
  const int tx = tid & 15, ty = tid >> 4;
  const int lr = tid >> 3, lc0 = (tid & 7)*8;
  float pa[4][4] = {}, qa[4][4] = {};
  for(int kt=0; kt<C; kt+=32){
    __syncthreads();
    {
      const float* xs = xb + (size_t)(kt+lr)*NN + n0 + lc0;
      *(float4*)&Xs[lr][lc0]   = *(const float4*)xs;
      *(float4*)&Xs[lr][lc0+4] = *(const float4*)(xs+4);
      const float* w1 = Wt1 + (size_t)(kt+lr)*O + o0 + lc0;
      *(float4*)&W1s[lr][lc0]   = *(const float4*)w1;
      *(float4*)&W1s[lr][lc0+4] = *(const float4*)(w1+4);
      const float* wd = Wtd + (size_t)(kt+lr)*O + o0 + lc0;
      *(float4*)&Wds[lr][lc0]   = *(const float4*)wd;
      *(float4*)&Wds[lr][lc0+4] = *(const float4*)(wd+4);
    }
    __syncthreads();
    #pragma unroll
    for(int cc=0;cc<32;cc++){
      float a[4], w[4], d[4];
      *(float4*)a = *(const float4*)&Xs[cc][ty*4];
      *(float4*)w = *(const float4*)&W1s[cc][tx*4];
      *(float4*)d = *(const float4*)&Wds[cc][tx*4];
      #pragma unroll
      for(int i=0;i<4;i++)
        #pragma unroll
        for(int j=0;j<4;j++){
          pa[i][j] += a[i]*w[j];
          qa[i][j] += a[i]*d[j];
        }
    }
  }
  #pragma unroll
  for(int i=0;i<4;i++){
    size_t t = (size_t)t0 + ty*4 + i;
    #pragma unroll
    for(int j=0;j<4;j++){
      int o = o0 + tx*4 + j;
      P[t*O + o] = pa[i][j];
      Q[t*O + o] = qa[i][j] + bias[o];
    }
  }
}

// ---------------- P/Q for C=3 (cheap scalar path) ----------------
template<int C, int O>
__global__ __launch_bounds__(256)
void pq_kernel(const float* __restrict__ x, const float* __restrict__ W,
               const float* __restrict__ bias,
               float* __restrict__ P, float* __restrict__ Q){
  constexpr int G = 256/O;
  constexpr int T = 8/G;
  constexpr int CP = ((C+3)/4)*4;
  __shared__ float xs[8][CP];
  const int tid = threadIdx.x;
  const long long t0b = (long long)blockIdx.x*8;
  const int b = (int)(t0b / NN), n0 = (int)(t0b % NN);
  const float* xb = x + (size_t)b*C*NN;
  for(int e=tid; e<8*C; e+=256){
    int tt = e / C, c = e % C;
    xs[tt][c] = xb[(size_t)c*NN + n0 + tt];
  }
  __syncthreads();

  const int o = tid % O, g = tid / O;
  const float* wrow = W + (size_t)o*2*C;
  float p[T], q[T];
  #pragma unroll
  for(int jt=0;jt<T;jt++){ p[jt]=0.f; q[jt]=0.f; }

  float w0=wrow[0], w1v=wrow[1], w2v=wrow[2];
  float d0=wrow[C+0]-w0, d1=wrow[C+1]-w1v, d2=wrow[C+2]-w2v;
  #pragma unroll
  for(int jt=0;jt<T;jt++){
    float a0=xs[g*T+jt][0], a1=xs[g*T+jt][1], a2=xs[g*T+jt][2];
    p[jt] += w0*a0; p[jt] += w1v*a1; p[jt] += w2v*a2;
    q[jt] += d0*a0; q[jt] += d1*a1; q[jt] += d2*a2;
  }
  float bv = bias[o];
  #pragma unroll
  for(int jt=0;jt<T;jt++){
    size_t t = (size_t)t0b + g*T + jt;
    P[t*O + o] = p[jt];
    Q[t*O + o] = q[jt] + bv;
  }
}

// ---------------- edge reduce: CH channels per pass (L2-locality split) ----------------
template<int O, int CH>
__global__ void edge_reduce_kernel(const float* __restrict__ P, const float* __restrict__ Q,
                                   const int* __restrict__ idx,
                                   float* __restrict__ maxh, float* __restrict__ minh,
                                   double* __restrict__ ssum, double* __restrict__ ssq){
  const int o = blockIdx.y*CH + threadIdx.x;
  const int TN = 8;
  int t0 = blockIdx.x*TN;
  double s = 0.0, s2 = 0.0;
  for(int t=t0;t<t0+TN;t++){
    int bbase = (t/NN)*NN;
    float q = Q[(size_t)t*O + o];
    const int* id = idx + (size_t)t*KK;
    float mx = NEG_FLT, mn = POS_FLT;
    for(int k=0;k<KK;k++){
      int m = id[k];
      float h = P[(size_t)(bbase+m)*O + o] + q;
      mx = fmaxf(mx, h); mn = fminf(mn, h);
      s += (double)h; s2 += (double)h*(double)h;
    }
    maxh[(size_t)t*O + o] = mx;
    minh[(size_t)t*O + o] = mn;
  }
  atomicAdd(&ssum[o], s);
  atomicAdd(&ssq[o], s2);
}

// ---------------- BN stat finalize ----------------
__global__ void finalize_stats(const double* __restrict__ ssum, const double* __restrict__ ssq,
                               const float* __restrict__ g, const float* __restrict__ beta,
                               float* __restrict__ scale, float* __restrict__ shift,
                               int O, double cnt){
  int o = blockIdx.x*blockDim.x + threadIdx.x;
  if(o >= O) return;
  double m = ssum[o]/cnt;
  double v = ssq[o]/cnt - m*m;
  if(v < 0.0) v = 0.0;
  float sc = g[o]/sqrtf((float)v + 1e-5f);
  scale[o] = sc;
  shift[o] = beta[o] - (float)m*sc;
}

// ---------------- edge apply: writes f32 xout + bf16 cat slice ----------------
template<int O>
__global__ void edge_apply_kernel(const float* __restrict__ maxh, const float* __restrict__ minh,
                                  const float* __restrict__ scale, const float* __restrict__ shift,
                                  float* __restrict__ xout, unsigned short* __restrict__ cat,
                                  int catOff){
  int i = blockIdx.x*blockDim.x + threadIdx.x;
  if(i >= BB*NN*O) return;
  int o = i % O; int t = i / O; int n = t % NN; int b = t / NN;
  float sc = scale[o];
  float v = sc >= 0.f ? maxh[i] : minh[i];
  float y = lrelu02(v*sc + shift[o]);
  xout[((size_t)b*O + o)*NN + n] = y;
  cat[(size_t)t*512 + catOff + o] = f2bf(y);
}

// ---------------- bf16 MFMA GEMM ----------------
__global__ __launch_bounds__(256)
void gemm_bf16_kernel(const unsigned short* __restrict__ A, const unsigned short* __restrict__ Bw,
                      const float* __restrict__ bias, float* __restrict__ Cout,
                      int M, int Kd, int O){
  __shared__ unsigned short Al[128*72];
  __shared__ unsigned short Bl[128*72];
  const int m0 = blockIdx.x*128, o0 = blockIdx.y*128;
  const int tid = threadIdx.x;
  const int w = tid >> 6, l = tid & 63;
  const int wm = (w>>1)*64, wn = (w&1)*64;
  const int sr = tid >> 1;
  const int sc = (tid & 1)*32;
  const int frow = l & 15, kgrp = (l>>4)*8;
  f32x4 acc[4][4] = {};

  for(int kt=0; kt<Kd; kt+=64){
    const unsigned short* Ap = A  + (size_t)(m0+sr)*Kd + kt + sc;
    const unsigned short* Bp = Bw + (size_t)(o0+sr)*Kd + kt + sc;
    __syncthreads();
    *(short8*)&Al[sr*72 + sc     ] = *(const short8*)(Ap);
    *(short8*)&Al[sr*72 + sc +  8] = *(const short8*)(Ap+8);
    *(short8*)&Al[sr*72 + sc + 16] = *(const short8*)(Ap+16);
    *(short8*)&Al[sr*72 + sc + 24] = *(const short8*)(Ap+24);
    *(short8*)&Bl[sr*72 + sc     ] = *(const short8*)(Bp);
    *(short8*)&Bl[sr*72 + sc +  8] = *(const short8*)(Bp+8);
    *(short8*)&Bl[sr*72 + sc + 16] = *(const short8*)(Bp+16);
    *(short8*)&Bl[sr*72 + sc + 24] = *(const short8*)(Bp+24);
    __syncthreads();
    #pragma unroll
    for(int ks=0; ks<2; ks++){
      short8 af[4], bf[4];
      #pragma unroll
      for(int f=0; f<4; f++){
        af[f] = *(const short8*)&Al[(wm+f*16+frow)*72 + ks*32 + kgrp];
        bf[f] = *(const short8*)&Bl[(wn+f*16+frow)*72 + ks*32 + kgrp];
      }
      #pragma unroll
      for(int i=0;i<4;i++)
        #pragma unroll
        for(int j=0;j<4;j++)
          acc[i][j] = __builtin_amdgcn_mfma_f32_16x16x32_bf16(af[i], bf[j], acc[i][j], 0,0,0);
    }
  }
  const int crow = (l>>4)*4, ccol = l & 15;
  #pragma unroll
  for(int i=0;i<4;i++){
    #pragma unroll
    for(int j=0;j<4;j++){
      int oc = o0 + wn + j*16 + ccol;
      float bv = bias[oc];
      #pragma unroll
      for(int r=0;r<4;r++){
        int mr = m0 + wm + i*16 + crow + r;
        Cout[(size_t)mr*O + oc] = acc[i][j][r] + bv;
      }
    }
  }
}

// ---------------- f32 -> bf16 convert ----------------
__global__ void wcvt_kernel(const float* __restrict__ in, unsigned short* __restrict__ out, int n){
  int i = blockIdx.x*blockDim.x + threadIdx.x;
  if(i < n) out[i] = f2bf(in[i]);
}

// ---------------- column stats over M rows ----------------
__global__ void colstats_kernel(const float* __restrict__ H, double* __restrict__ ssum,
                                double* __restrict__ ssq, int O){
  int o  = blockIdx.x*blockDim.x + threadIdx.x;
  int m0 = blockIdx.y*64;
  double s=0.0, s2=0.0;
  for(int m=m0;m<m0+64;m++){
    float h = H[(size_t)m*O + o];
    s += (double)h; s2 += (double)h*(double)h;
  }
  atomicAdd(&ssum[o], s); atomicAdd(&ssq[o], s2);
}

__global__ void bn_lrelu_bf16_kernel(const float* __restrict__ H, const float* __restrict__ scale,
                                     const float* __restrict__ shift, unsigned short* __restrict__ Hb,
                                     int O, long long total){
  long long i = (long long)blockIdx.x*blockDim.x + threadIdx.x;
  if(i >= total) return;
  int o = (int)(i % O);
  Hb[i] = f2bf(lrelu02(H[i]*scale[o] + shift[o]));
}

// ---------------- per-(b,o) max/min over n ----------------
__global__ void init_minmax_kernel(int* __restrict__ gmax, int* __restrict__ gmin, int n){
  int i = blockIdx.x*blockDim.x + threadIdx.x;
  if(i < n){ gmax[i] = -2147483647-1; gmin[i] = 2147483647; }
}

__global__ void colminmax_kernel(const float* __restrict__ H, int* __restrict__ gmax,
                                 int* __restrict__ gmin, int O){
  int o  = blockIdx.x*blockDim.x + threadIdx.x;
  int b  = blockIdx.y >> 4;
  int nt = blockIdx.y & 15;
  const float* Hp = H + (size_t)(b*NN + nt*256)*O + o;
  float mx = NEG_FLT, mn = POS_FLT;
  for(int i2=0;i2<256;i2++){
    float h = Hp[(size_t)i2*O];
    mx = fmaxf(mx, h); mn = fminf(mn, h);
  }
  atomicMax(&gmax[b*O + o], f2ord(mx));
  atomicMin(&gmin[b*O + o], f2ord(mn));
}

__global__ void t_apply_kernel(const int* __restrict__ gmax, const int* __restrict__ gmin,
                               const float* __restrict__ scale, const float* __restrict__ shift,
                               float* __restrict__ tfeat, int O){
  int i = blockIdx.x*blockDim.x + threadIdx.x;
  if(i >= BB*O) return;
  int o = i % O;
  float sc = scale[o];
  int ov = sc >= 0.f ? gmax[i] : gmin[i];
  float v = __int_as_float(ov >= 0 ? ov : (ov ^ 0x7fffffff));
  float y = v*sc + shift[o];
  tfeat[i] = fmaxf(y, 0.f);
}

// ---------------- FC + batch-BN(4) + relu ----------------
__global__ __launch_bounds__(128)
void fc_bn_relu_kernel(const float* __restrict__ X, const float* __restrict__ W,
                       const float* __restrict__ bias, const float* __restrict__ g,
                       const float* __restrict__ beta, float* __restrict__ Y,
                       int Cin, int Cout){
  int j = blockIdx.x;
  __shared__ float red[4][128];
  float a0=0,a1=0,a2=0,a3=0;
  const float* w = W + (size_t)j*Cin;
  for(int c=threadIdx.x;c<Cin;c+=128){
    float wv = w[c];
    a0 += X[c]*wv; a1 += X[Cin+c]*wv; a2 += X[2*Cin+c]*wv; a3 += X[3*Cin+c]*wv;
  }
  red[0][threadIdx.x]=a0; red[1][threadIdx.x]=a1; red[2][threadIdx.x]=a2; red[3][threadIdx.x]=a3;
  __syncthreads();
  for(int s=64;s>=1;s>>=1){
    if(threadIdx.x < s){
      #pragma unroll
      for(int b=0;b<4;b++) red[b][threadIdx.x] += red[b][threadIdx.x+s];
    }
    __syncthreads();
  }
  if(threadIdx.x == 0){
    float h[4];
    #pragma unroll
    for(int b=0;b<4;b++) h[b] = red[b][0] + bias[j];
    float m = 0.25f*(h[0]+h[1]+h[2]+h[3]);
    float var = 0.f;
    #pragma unroll
    for(int b=0;b<4;b++){ float d = h[b]-m; var += d*d; }
    var *= 0.25f;
    float sc = g[j]/sqrtf(var + 1e-5f);
    #pragma unroll
    for(int b=0;b<4;b++){
      float y = (h[b]-m)*sc + beta[j];
      Y[(size_t)b*Cout + j] = fmaxf(y, 0.f);
    }
  }
}

__global__ __launch_bounds__(64)
void fc3_kernel(const float* __restrict__ X, const float* __restrict__ W,
                const float* __restrict__ bias, float* __restrict__ out){
  int t = threadIdx.x; int b = t >> 4; int j = t & 15;
  float v;
  if(j < 12){
    float acc = 0.f;
    const float* w = W + (size_t)j*256;
    const float* xb = X + (size_t)b*256;
    for(int c=0;c<256;c++) acc += xb[c]*w[c];
    v = acc + bias[j];
    if(j==0 || j==5 || j==10) v += 1.f;
  } else {
    v = (j==15) ? 1.f : 0.f;
  }
  out[t] = v;
}

// ---------------- host-side kNN: 2 batches materialized at a time ----------------
template<int C>
static void run_knn(const float* xin, const float* xxb, float* distA, float* distB,
                    int* idxb, hipStream_t stream){
  for(int half=0; half<2; half++){
    int b0 = half*2;
    for(int j=0;j<2;j++){
      int b = b0 + j;
      float* dd = j==0 ? distA : distB;
      const float* xb = xin + (size_t)b*C*NN;
      const float* xx = xxb + (size_t)b*NN;
      if constexpr(C == 3){
        dist3_kernel<<<dim3(NN/1024, NN), 256, 0, stream>>>(xb, xx, dd);
      } else {
        dist_kernel<C><<<dim3(NN/128, NN/128), 256, 0, stream>>>(xb, xx, dd);
      }
    }
    select_kernel<<<2*NN/4, 256, 0, stream>>>(distA, distB, idxb + (size_t)b0*NN*KK);
  }
}

// ---------------- host-side edge block ----------------
template<int C, int O>
static void run_edge_block(const float* xin, const float* W, const float* bias,
                           const float* g, const float* e, float* xout, int catOff,
                           float* xxb, int* idxb, float* P, float* Q,
                           float* maxh, float* minh, float* distB,
                           float* Wt1, float* Wtd,
                           double* ssum, double* ssq,
                           float* scaleb, float* shiftb, unsigned short* catb, hipStream_t stream){
  xx_kernel<C><<<(BB*NN+255)/256, 256, 0, stream>>>(xin, xxb);
  run_knn<C>(xin, xxb, P /*distA = P..minh*/, distB, idxb, stream);
  if constexpr(C >= 32){
    wt_kernel<C,O><<<(C*O+255)/256, 256, 0, stream>>>(W, Wt1, Wtd);
    pq_gemm_kernel<C,O><<<dim3(BB*NN/64, O/64), 256, 0, stream>>>(xin, Wt1, Wtd, bias, P, Q);
  } else {
    pq_kernel<C,O><<<BB*NN/8, 256, 0, stream>>>(xin, W, bias, P, Q);
  }
  hipMemsetAsync(ssum, 0, O*sizeof(double), stream);
  hipMemsetAsync(ssq,  0, O*sizeof(double), stream);
  constexpr int CH = (O > 128) ? 128 : O;
  edge_reduce_kernel<O,CH><<<dim3(BB*NN/8, O/CH), CH, 0, stream>>>(P, Q, idxb, maxh, minh, ssum, ssq);
  finalize_stats<<<(O+255)/256, 256, 0, stream>>>(ssum, ssq, g, e, scaleb, shiftb, O, (double)BB*NN*KK);
  edge_apply_kernel<O><<<(BB*NN*O+255)/256, 256, 0, stream>>>(maxh, minh, scaleb, shiftb, xout, catb, catOff);
}

extern "C" void kernel_launch(void* const* d_in, const int* in_sizes, int n_in,
                              void* d_out, int out_size, void* d_ws, size_t ws_size,
                              hipStream_t stream){
  (void)in_sizes; (void)n_in; (void)out_size; (void)ws_size;
  const float* x   = (const float*)d_in[0];
  const float* w1  = (const float*)d_in[1];  const float* b1 = (const float*)d_in[2];
  const float* g1  = (const float*)d_in[3];  const float* e1 = (const float*)d_in[4];
  const float* w2  = (const float*)d_in[5];  const float* b2 = (const float*)d_in[6];
  const float* g2  = (const float*)d_in[7];  const float* e2 = (const float*)d_in[8];
  const float* w3  = (const float*)d_in[9];  const float* b3 = (const float*)d_in[10];
  const float* g3  = (const float*)d_in[11]; const float* e3 = (const float*)d_in[12];
  const float* w4  = (const float*)d_in[13]; const float* b4 = (const float*)d_in[14];
  const float* g4  = (const float*)d_in[15]; const float* e4 = (const float*)d_in[16];
  const float* w5  = (const float*)d_in[17]; const float* b5 = (const float*)d_in[18];
  const float* g5  = (const float*)d_in[19]; const float* e5 = (const float*)d_in[20];
  const float* twp = (const float*)d_in[21]; const float* tbp = (const float*)d_in[22];
  const float* tg  = (const float*)d_in[23]; const float* te  = (const float*)d_in[24];
  const float* f1w = (const float*)d_in[25]; const float* f1b = (const float*)d_in[26];
  const float* f1g = (const float*)d_in[27]; const float* f1e = (const float*)d_in[28];
  const float* f2w = (const float*)d_in[29]; const float* f2b = (const float*)d_in[30];
  const float* f2g = (const float*)d_in[31]; const float* f2e = (const float*)d_in[32];
  const float* f3w = (const float*)d_in[33]; const float* f3b = (const float*)d_in[34];

  char* ws = (char*)d_ws;
  size_t off = 0;
  auto alloc = [&](size_t bytes)->void*{
    void* p = ws + off;
    off += (bytes + 255) & ~(size_t)255;
    return p;
  };
  int*    idxb  = (int*)   alloc((size_t)BB*NN*KK*4);
  float*  xxb   = (float*) alloc((size_t)BB*NN*4);
  float*  x1    = (float*) alloc((size_t)BB*64*NN*4);    // dead after block2 -> w5b
  float*  x2    = (float*) alloc((size_t)BB*64*NN*4);    // dead after block3 -> twb
  float*  x3    = (float*) alloc((size_t)BB*128*NN*4);
  float*  x4    = (float*) alloc((size_t)BB*256*NN*4);
  float*  P     = (float*) alloc((size_t)BB*NN*256*4);   // P..minh = distA (one batch, 64MB)
  float*  Q     = (float*) alloc((size_t)BB*NN*256*4);
  float*  maxh  = (float*) alloc((size_t)BB*NN*256*4);   // maxh+minh -> h5b after edge blocks
  float*  minh  = (float*) alloc((size_t)BB*NN*256*4);
  unsigned short* catb = (unsigned short*) alloc((size_t)BB*NN*512*2);
  float*  h5    = (float*) alloc((size_t)BB*NN*1024*4);  // distB during edge blocks; h5/h6 after
  float*  Wt1   = (float*) alloc((size_t)256*128*4);
  float*  Wtd   = (float*) alloc((size_t)256*128*4);
  double* ssum  = (double*)alloc(1024*8);
  double* ssq   = (double*)alloc(1024*8);
  float*  scaleb= (float*) alloc(1024*4);
  float*  shiftb= (float*) alloc(1024*4);
  int*    gmax  = (int*)   alloc((size_t)BB*1024*4);
  int*    gmin  = (int*)   alloc((size_t)BB*1024*4);
  float*  tfeat = (float*) alloc((size_t)BB*1024*4);
  float*  y1    = (float*) alloc((size_t)BB*512*4);
  float*  y2    = (float*) alloc((size_t)BB*256*4);

  unsigned short* w5b  = (unsigned short*)x1;
  unsigned short* twb  = (unsigned short*)x2;
  unsigned short* h5b  = (unsigned short*)maxh;
  float*          h6   = h5;

  run_edge_block<3,  64 >(x,  w1, b1, g1, e1, x1, 0,   xxb, idxb, P, Q, maxh, minh, h5, Wt1, Wtd, ssum, ssq, scaleb, shiftb, catb, stream);
  run_edge_block<64, 64 >(x1, w2, b2, g2, e2, x2, 64,  xxb, idxb, P, Q, maxh, minh, h5, Wt1, Wtd, ssum, ssq, scaleb, shiftb, catb, stream);
  run_edge_block<64, 128>(x2, w3, b3, g3, e3, x3, 128, xxb, idxb, P, Q, maxh, minh, h5, Wt1, Wtd, ssum, ssq, scaleb, shiftb, catb, stream);
  run_edge_block<128,256>(x3, w4, b4, g4, e4, x4, 256, xxb, idxb, P, Q, maxh, minh, h5, Wt1, Wtd, ssum, ssq, scaleb, shiftb, catb, stream);

  const int M = BB*NN; // 16384
  wcvt_kernel<<<(1024*512 +255)/256, 256, 0, stream>>>(w5,  w5b, 1024*512);
  wcvt_kernel<<<(1024*1024+255)/256, 256, 0, stream>>>(twp, twb, 1024*1024);

  gemm_bf16_kernel<<<dim3(M/128, 1024/128), 256, 0, stream>>>(catb, w5b, b5, h5, M, 512, 1024);
  hipMemsetAsync(ssum, 0, 1024*8, stream);
  hipMemsetAsync(ssq,  0, 1024*8, stream);
  colstats_kernel<<<dim3(1024/256, M/64), 256, 0, stream>>>(h5, ssum, ssq, 1024);
  finalize_stats<<<4, 256, 0, stream>>>(ssum, ssq, g5, e5, scaleb, shiftb, 1024, (double)M);
  bn_lrelu_bf16_kernel<<<(int)(((long long)M*1024+255)/256), 256, 0, stream>>>(h5, scaleb, shiftb, h5b, 1024, (long long)M*1024);

  gemm_bf16_kernel<<<dim3(M/128, 1024/128), 256, 0, stream>>>(h5b, twb, tbp, h6, M, 1024, 1024);
  hipMemsetAsync(ssum, 0, 1024*8, stream);
  hipMemsetAsync(ssq,  0, 1024*8, stream);
  init_minmax_kernel<<<(BB*1024+255)/256, 256, 0, stream>>>(gmax, gmin, BB*1024);
  colstats_kernel<<<dim3(1024/256, M/64), 256, 0, stream>>>(h6, ssum, ssq, 1024);
  colminmax_kernel<<<dim3(1024/256, BB*(NN/256)), 256, 0, stream>>>(h6, gmax, gmin, 1024);
  finalize_stats<<<4, 256, 0, stream>>>(ssum, ssq, tg, te, scaleb, shiftb, 1024, (double)M);
  t_apply_kernel<<<(BB*1024+255)/256, 256, 0, stream>>>(gmax, gmin, scaleb, shiftb, tfeat, 1024);

  fc_bn_relu_kernel<<<512, 128, 0, stream>>>(tfeat, f1w, f1b, f1g, f1e, y1, 1024, 512);
  fc_bn_relu_kernel<<<256, 128, 0, stream>>>(y1, f2w, f2b, f2g, f2e, y2, 512, 256);
  fc3_kernel<<<1, 64, 0, stream>>>(y2, f3w, f3b, (float*)d_out);
}

// Round 9
// 1887.053 us; speedup vs baseline: 1.0485x; 1.0485x over previous
//
#include <hip/hip_runtime.h>

#define BB 4
#define NN 4096
#define KK 40

#define NEG_FLT (-3.402823466e38f)
#define POS_FLT (3.402823466e38f)

typedef __attribute__((ext_vector_type(8))) short short8;
typedef __attribute__((ext_vector_type(4))) float f32x4;

__device__ __forceinline__ float lrelu02(float v){ return v > 0.f ? v : 0.2f*v; }
__device__ __forceinline__ int f2ord(float f){ int u = __float_as_int(f); return u >= 0 ? u : (u ^ 0x7fffffff); }
__device__ __forceinline__ unsigned ordu(float f){
  unsigned u = __float_as_uint(f);
  return (u & 0x80000000u) ? ~u : (u | 0x80000000u);
}
__device__ __forceinline__ unsigned long long packkey(float v, int m){
  return ((unsigned long long)ordu(v) << 32) | (unsigned)(~m);
}
__device__ __forceinline__ unsigned short f2bf(float f){   // RNE f32->bf16
  unsigned u = __float_as_uint(f);
  unsigned r = u + 0x7fffu + ((u>>16)&1u);
  return (unsigned short)(r>>16);
}

// ---------------- xx = sum_c x^2 ----------------
template<int C>
__global__ void xx_kernel(const float* __restrict__ x, float* __restrict__ xx){
  int i = blockIdx.x*blockDim.x + threadIdx.x;
  if(i >= BB*NN) return;
  int b = i / NN, n = i % NN;
  const float* xb = x + (size_t)b*C*NN + n;
  float s = 0.f;
  #pragma unroll
  for(int c=0;c<C;c++){ float v = xb[(size_t)c*NN]; s += v*v; }
  xx[i] = s;
}

// ---------------- distance matrix: 128x128 fp32 tile, K-step 16, SYMMETRIC ----------------
template<int C>
__global__ __launch_bounds__(256)
void dist_kernel(const float* __restrict__ xb, const float* __restrict__ xx,
                 float* __restrict__ dist){
  const int n0 = blockIdx.y*128, m0 = blockIdx.x*128;
  if(m0 < n0) return;
  __shared__ float As[16][132];
  __shared__ float Bs[16][132];
  const int tid = threadIdx.x;
  const int tx = tid & 15, ty = tid >> 4;
  const int lr = tid >> 4;           // staging k-row 0..15
  const int lc0 = (tid & 15)*8;      // staging col base
  float acc[8][8] = {};
  for(int kt=0; kt<C; kt+=16){
    __syncthreads();
    {
      const float* an = xb + (size_t)(kt+lr)*NN + n0 + lc0;
      const float* am = xb + (size_t)(kt+lr)*NN + m0 + lc0;
      *(float4*)&As[lr][lc0]   = *(const float4*)an;
      *(float4*)&As[lr][lc0+4] = *(const float4*)(an+4);
      *(float4*)&Bs[lr][lc0]   = *(const float4*)am;
      *(float4*)&Bs[lr][lc0+4] = *(const float4*)(am+4);
    }
    __syncthreads();
    #pragma unroll
    for(int cc=0;cc<16;cc++){
      float a[8], b[8];
      *(float4*)&a[0] = *(const float4*)&As[cc][ty*8];
      *(float4*)&a[4] = *(const float4*)&As[cc][ty*8+4];
      *(float4*)&b[0] = *(const float4*)&Bs[cc][tx*8];
      *(float4*)&b[4] = *(const float4*)&Bs[cc][tx*8+4];
      #pragma unroll
      for(int i=0;i<8;i++)
        #pragma unroll
        for(int j=0;j<8;j++) acc[i][j] += a[i]*b[j];
    }
  }
  float xmv[8], xnv[8];
  #pragma unroll
  for(int j=0;j<8;j++) xmv[j] = xx[m0 + tx*8 + j];
  #pragma unroll
  for(int i=0;i<8;i++) xnv[i] = xx[n0 + ty*8 + i];
  #pragma unroll
  for(int i=0;i<8;i++){
    int n = n0 + ty*8 + i;
    float xn = xnv[i];
    float4 r0, r1;
    r0.x = 2.f*acc[i][0] - xn - xmv[0];
    r0.y = 2.f*acc[i][1] - xn - xmv[1];
    r0.z = 2.f*acc[i][2] - xn - xmv[2];
    r0.w = 2.f*acc[i][3] - xn - xmv[3];
    r1.x = 2.f*acc[i][4] - xn - xmv[4];
    r1.y = 2.f*acc[i][5] - xn - xmv[5];
    r1.z = 2.f*acc[i][6] - xn - xmv[6];
    r1.w = 2.f*acc[i][7] - xn - xmv[7];
    *(float4*)(dist + (size_t)n*NN + m0 + tx*8)     = r0;
    *(float4*)(dist + (size_t)n*NN + m0 + tx*8 + 4) = r1;
  }
  if(m0 != n0){
    #pragma unroll
    for(int j=0;j<8;j++){
      int m = m0 + tx*8 + j;
      float xm = xmv[j];
      float4 r0, r1;
      r0.x = 2.f*acc[0][j] - xnv[0] - xm;
      r0.y = 2.f*acc[1][j] - xnv[1] - xm;
      r0.z = 2.f*acc[2][j] - xnv[2] - xm;
      r0.w = 2.f*acc[3][j] - xnv[3] - xm;
      r1.x = 2.f*acc[4][j] - xnv[4] - xm;
      r1.y = 2.f*acc[5][j] - xnv[5] - xm;
      r1.z = 2.f*acc[6][j] - xnv[6] - xm;
      r1.w = 2.f*acc[7][j] - xnv[7] - xm;
      *(float4*)(dist + (size_t)m*NN + n0 + ty*8)     = r0;
      *(float4*)(dist + (size_t)m*NN + n0 + ty*8 + 4) = r1;
    }
  }
}

// branch-free sorted-insert ladder on NAMED registers (no refs -> no scratch)
#define INSQ(vf, mi) do{ \
  unsigned long long _pk = packkey((vf),(mi)); \
  if(_pk > t7){ \
    unsigned long long _lo; \
    _lo = _pk < t0 ? _pk : t0;  t0 = _pk > t0 ? _pk : t0;  _pk = _lo; \
    _lo = _pk < t1 ? _pk : t1;  t1 = _pk > t1 ? _pk : t1;  _pk = _lo; \
    _lo = _pk < t2 ? _pk : t2;  t2 = _pk > t2 ? _pk : t2;  _pk = _lo; \
    _lo = _pk < t3 ? _pk : t3;  t3 = _pk > t3 ? _pk : t3;  _pk = _lo; \
    _lo = _pk < t4 ? _pk : t4;  t4 = _pk > t4 ? _pk : t4;  _pk = _lo; \
    _lo = _pk < t5 ? _pk : t5;  t5 = _pk > t5 ? _pk : t5;  _pk = _lo; \
    _lo = _pk < t6 ? _pk : t6;  t6 = _pk > t6 ? _pk : t6;  _pk = _lo; \
    t7 = _pk > t7 ? _pk : t7; \
  } \
}while(0)

// ---------------- top-K over materialized dist rows (C>=64 path) ----------------
__global__ __launch_bounds__(256)
void select_kernel(const float* __restrict__ dA, const float* __restrict__ dB,
                   int* __restrict__ idx){
  const int wid = threadIdx.x >> 6;
  const int lane = threadIdx.x & 63;
  const int r = blockIdx.x*4 + wid;            // 0..8191 (two batches)
  const float* row = (r < NN) ? (dA + (size_t)r*NN) : (dB + (size_t)(r-NN)*NN);

  unsigned long long t0=0,t1=0,t2=0,t3=0,t4=0,t5=0,t6=0,t7=0;
  unsigned long long done = 0ull;

  #pragma unroll 4
  for(int j=0;j<16;j++){
    float4 v = *(const float4*)(row + j*256 + lane*4);
    int mb = j*256 + lane*4;
    INSQ(v.x, mb+0); INSQ(v.y, mb+1); INSQ(v.z, mb+2); INSQ(v.w, mb+3);
  }

  __shared__ int outbuf[4][KK];
  #pragma unroll 1
  for(int k=0;k<KK;k++){
    unsigned long long wv = t0;
    #pragma unroll
    for(int off=32; off; off>>=1){
      unsigned long long ov = __shfl_xor(wv, off, 64);
      wv = ov > wv ? ov : wv;
    }
    int m = (int)(~(unsigned)wv);
    if(lane == ((m>>2)&63)){
      done |= 1ull << (((m>>8)<<2) | (m&3));
      t0=t1;t1=t2;t2=t3;t3=t4;t4=t5;t5=t6;t6=t7;t7=0;
      if(t0 == 0ull){
        #pragma unroll 1
        for(int j=0;j<16;j++){
          float4 v = *(const float4*)(row + j*256 + lane*4);
          int mb = j*256 + lane*4;
          if(!((done>>(j*4+0))&1)) INSQ(v.x, mb+0);
          if(!((done>>(j*4+1))&1)) INSQ(v.y, mb+1);
          if(!((done>>(j*4+2))&1)) INSQ(v.z, mb+2);
          if(!((done>>(j*4+3))&1)) INSQ(v.w, mb+3);
        }
      }
    }
    if(lane == 0) outbuf[wid][k] = m;
  }
  if(lane < KK) idx[(size_t)r*KK + lane] = outbuf[wid][lane];
}

// ---------------- fused C=3 kNN: distances on the fly, no dist buffer ----------------
// distance chain is identical to the old dist3_kernel (s=c0*a; s+=c1*b; s+=c2*c;
// v = 2*s - xn - xm) -> bit-identical keys -> identical top-40.
__global__ __launch_bounds__(256)
void select3_kernel(const float* __restrict__ x, const float* __restrict__ xx,
                    int* __restrict__ idx){
  const int wid = threadIdx.x >> 6;
  const int lane = threadIdx.x & 63;
  const int r = blockIdx.x*4 + wid;            // 0..BB*NN-1
  const int b = r / NN, n = r % NN;
  const float* xb  = x + (size_t)b*3*NN;
  const float* xxb = xx + (size_t)b*NN;
  const float c0 = xb[n], c1 = xb[NN+n], c2 = xb[2*NN+n];
  const float xn = xxb[n];

  unsigned long long t0=0,t1=0,t2=0,t3=0,t4=0,t5=0,t6=0,t7=0;
  unsigned long long done = 0ull;

  #pragma unroll 4
  for(int j=0;j<16;j++){
    int mb = j*256 + lane*4;
    float4 a  = *(const float4*)(xb + mb);
    float4 bb = *(const float4*)(xb + NN + mb);
    float4 c  = *(const float4*)(xb + 2*NN + mb);
    float4 xm = *(const float4*)(xxb + mb);
    float vx, vy, vz, vw;
    { float s = c0*a.x; s += c1*bb.x; s += c2*c.x; vx = 2.f*s - xn - xm.x; }
    { float s = c0*a.y; s += c1*bb.y; s += c2*c.y; vy = 2.f*s - xn - xm.y; }
    { float s = c0*a.z; s += c1*bb.z; s += c2*c.z; vz = 2.f*s - xn - xm.z; }
    { float s = c0*a.w; s += c1*bb.w; s += c2*c.w; vw = 2.f*s - xn - xm.w; }
    INSQ(vx, mb+0); INSQ(vy, mb+1); INSQ(vz, mb+2); INSQ(vw, mb+3);
  }

  __shared__ int outbuf[4][KK];
  #pragma unroll 1
  for(int k=0;k<KK;k++){
    unsigned long long wv = t0;
    #pragma unroll
    for(int off=32; off; off>>=1){
      unsigned long long ov = __shfl_xor(wv, off, 64);
      wv = ov > wv ? ov : wv;
    }
    int m = (int)(~(unsigned)wv);
    if(lane == ((m>>2)&63)){
      done |= 1ull << (((m>>8)<<2) | (m&3));
      t0=t1;t1=t2;t2=t3;t3=t4;t4=t5;t5=t6;t6=t7;t7=0;
      if(t0 == 0ull){
        // rare rebuild: recompute distances, skipping extracted
        #pragma unroll 1
        for(int j=0;j<16;j++){
          int mb = j*256 + lane*4;
          float4 a  = *(const float4*)(xb + mb);
          float4 bb = *(const float4*)(xb + NN + mb);
          float4 c  = *(const float4*)(xb + 2*NN + mb);
          float4 xm = *(const float4*)(xxb + mb);
          float vx, vy, vz, vw;
          { float s = c0*a.x; s += c1*bb.x; s += c2*c.x; vx = 2.f*s - xn - xm.x; }
          { float s = c0*a.y; s += c1*bb.y; s += c2*c.y; vy = 2.f*s - xn - xm.y; }
          { float s = c0*a.z; s += c1*bb.z; s += c2*c.z; vz = 2.f*s - xn - xm.z; }
          { float s = c0*a.w; s += c1*bb.w; s += c2*c.w; vw = 2.f*s - xn - xm.w; }
          if(!((done>>(j*4+0))&1)) INSQ(vx, mb+0);
          if(!((done>>(j*4+1))&1)) INSQ(vy, mb+1);
          if(!((done>>(j*4+2))&1)) INSQ(vz, mb+2);
          if(!((done>>(j*4+3))&1)) INSQ(vw, mb+3);
        }
      }
    }
    if(lane == 0) outbuf[wid][k] = m;
  }
  if(lane < KK) idx[(size_t)r*KK + lane] = outbuf[wid][lane];
}

// ---------------- W transpose + delta ----------------
template<int C, int O>
__global__ void wt_kernel(const float* __restrict__ w, float* __restrict__ Wt1,
                          float* __restrict__ Wtd){
  int i = blockIdx.x*256 + threadIdx.x;
  if(i >= C*O) return;
  int c = i / O, o = i % O;
  float a = w[(size_t)o*2*C + c];
  float b = w[(size_t)o*2*C + C + c];
  Wt1[i] = a; Wtd[i] = b - a;
}

// ---------------- pq as dual-output fp32 GEMM ----------------
template<int C, int O>
__global__ __launch_bounds__(256)
void pq_gemm_kernel(const float* __restrict__ x, const float* __restrict__ Wt1,
                    const float* __restrict__ Wtd, const float* __restrict__ bias,
                    float* __restrict__ P, float* __restrict__ Q){
  __shared__ float Xs[32][68];
  __shared__ float W1s[32][68];
  __shared__ float Wds[32][68];
  const int t0 = blockIdx.x*64;
  const int o0 = blockIdx.y*64;
  const int b  = t0 / NN, n0 = t0 % NN;
  const float* xb = x + (size_t)b*C*NN;
  const int tid = threadIdx.x;
  const int tx = tid & 15, ty = tid >> 4;
  const int lr = tid >> 3, lc0 = (tid & 7)*8;
  float pa[4][4] = {}, qa[4][4] = {};
  for(int kt=0; kt<C; kt+=32){
    __syncthreads();
    {
      const float* xs = xb + (size_t)(kt+lr)*NN + n0 + lc0;
      *(float4*)&Xs[lr][lc0]   = *(const float4*)xs;
      *(float4*)&Xs[lr][lc0+4] = *(const float4*)(xs+4);
      const float* w1 = Wt1 + (size_t)(kt+lr)*O + o0 + lc0;
      *(float4*)&W1s[lr][lc0]   = *(const float4*)w1;
      *(float4*)&W1s[lr][lc0+4] = *(const float4*)(w1+4);
      const float* wd = Wtd + (size_t)(kt+lr)*O + o0 + lc0;
      *(float4*)&Wds[lr][lc0]   = *(const float4*)wd;
      *(float4*)&Wds[lr][lc0+4] = *(const float4*)(wd+4);
    }
    __syncthreads();
    #pragma unroll
    for(int cc=0;cc<32;cc++){
      float a[4], w[4], d[4];
      *(float4*)a = *(const float4*)&Xs[cc][ty*4];
      *(float4*)w = *(const float4*)&W1s[cc][tx*4];
      *(float4*)d = *(const float4*)&Wds[cc][tx*4];
      #pragma unroll
      for(int i=0;i<4;i++)
        #pragma unroll
        for(int j=0;j<4;j++){
          pa[i][j] += a[i]*w[j];
          qa[i][j] += a[i]*d[j];
        }
    }
  }
  #pragma unroll
  for(int i=0;i<4;i++){
    size_t t = (size_t)t0 + ty*4 + i;
    #pragma unroll
    for(int j=0;j<4;j++){
      int o = o0 + tx*4 + j;
      P[t*O + o] = pa[i][j];
      Q[t*O + o] = qa[i][j] + bias[o];
    }
  }
}

// ---------------- P/Q for C=3 (cheap scalar path) ----------------
template<int C, int O>
__global__ __launch_bounds__(256)
void pq_kernel(const float* __restrict__ x, const float* __restrict__ W,
               const float* __restrict__ bias,
               float* __restrict__ P, float* __restrict__ Q){
  constexpr int G = 256/O;
  constexpr int T = 8/G;
  constexpr int CP = ((C+3)/4)*4;
  __shared__ float xs[8][CP];
  const int tid = threadIdx.x;
  const long long t0b = (long long)blockIdx.x*8;
  const int b = (int)(t0b / NN), n0 = (int)(t0b % NN);
  const float* xb = x + (size_t)b*C*NN;
  for(int e=tid; e<8*C; e+=256){
    int tt = e / C, c = e % C;
    xs[tt][c] = xb[(size_t)c*NN + n0 + tt];
  }
  __syncthreads();

  const int o = tid % O, g = tid / O;
  const float* wrow = W + (size_t)o*2*C;
  float p[T], q[T];
  #pragma unroll
  for(int jt=0;jt<T;jt++){ p[jt]=0.f; q[jt]=0.f; }

  float w0=wrow[0], w1v=wrow[1], w2v=wrow[2];
  float d0=wrow[C+0]-w0, d1=wrow[C+1]-w1v, d2=wrow[C+2]-w2v;
  #pragma unroll
  for(int jt=0;jt<T;jt++){
    float a0=xs[g*T+jt][0], a1=xs[g*T+jt][1], a2=xs[g*T+jt][2];
    p[jt] += w0*a0; p[jt] += w1v*a1; p[jt] += w2v*a2;
    q[jt] += d0*a0; q[jt] += d1*a1; q[jt] += d2*a2;
  }
  float bv = bias[o];
  #pragma unroll
  for(int jt=0;jt<T;jt++){
    size_t t = (size_t)t0b + g*T + jt;
    P[t*O + o] = p[jt];
    Q[t*O + o] = q[jt] + bv;
  }
}

// ---------------- edge reduce (single pass, O threads — R7 form) ----------------
template<int O>
__global__ void edge_reduce_kernel(const float* __restrict__ P, const float* __restrict__ Q,
                                   const int* __restrict__ idx,
                                   float* __restrict__ maxh, float* __restrict__ minh,
                                   double* __restrict__ ssum, double* __restrict__ ssq){
  const int o = threadIdx.x;
  const int TN = 8;
  int t0 = blockIdx.x*TN;
  double s = 0.0, s2 = 0.0;
  for(int t=t0;t<t0+TN;t++){
    int bbase = (t/NN)*NN;
    float q = Q[(size_t)t*O + o];
    const int* id = idx + (size_t)t*KK;
    float mx = NEG_FLT, mn = POS_FLT;
    for(int k=0;k<KK;k++){
      int m = id[k];
      float h = P[(size_t)(bbase+m)*O + o] + q;
      mx = fmaxf(mx, h); mn = fminf(mn, h);
      s += (double)h; s2 += (double)h*(double)h;
    }
    maxh[(size_t)t*O + o] = mx;
    minh[(size_t)t*O + o] = mn;
  }
  atomicAdd(&ssum[o], s);
  atomicAdd(&ssq[o], s2);
}

// ---------------- BN stat finalize ----------------
__global__ void finalize_stats(const double* __restrict__ ssum, const double* __restrict__ ssq,
                               const float* __restrict__ g, const float* __restrict__ beta,
                               float* __restrict__ scale, float* __restrict__ shift,
                               int O, double cnt){
  int o = blockIdx.x*blockDim.x + threadIdx.x;
  if(o >= O) return;
  double m = ssum[o]/cnt;
  double v = ssq[o]/cnt - m*m;
  if(v < 0.0) v = 0.0;
  float sc = g[o]/sqrtf((float)v + 1e-5f);
  scale[o] = sc;
  shift[o] = beta[o] - (float)m*sc;
}

// ---------------- edge apply ----------------
template<int O>
__global__ void edge_apply_kernel(const float* __restrict__ maxh, const float* __restrict__ minh,
                                  const float* __restrict__ scale, const float* __restrict__ shift,
                                  float* __restrict__ xout, unsigned short* __restrict__ cat,
                                  int catOff){
  int i = blockIdx.x*blockDim.x + threadIdx.x;
  if(i >= BB*NN*O) return;
  int o = i % O; int t = i / O; int n = t % NN; int b = t / NN;
  float sc = scale[o];
  float v = sc >= 0.f ? maxh[i] : minh[i];
  float y = lrelu02(v*sc + shift[o]);
  xout[((size_t)b*O + o)*NN + n] = y;
  cat[(size_t)t*512 + catOff + o] = f2bf(y);
}

// ---------------- bf16 MFMA GEMM ----------------
__global__ __launch_bounds__(256)
void gemm_bf16_kernel(const unsigned short* __restrict__ A, const unsigned short* __restrict__ Bw,
                      const float* __restrict__ bias, float* __restrict__ Cout,
                      int M, int Kd, int O){
  __shared__ unsigned short Al[128*72];
  __shared__ unsigned short Bl[128*72];
  const int m0 = blockIdx.x*128, o0 = blockIdx.y*128;
  const int tid = threadIdx.x;
  const int w = tid >> 6, l = tid & 63;
  const int wm = (w>>1)*64, wn = (w&1)*64;
  const int sr = tid >> 1;
  const int sc = (tid & 1)*32;
  const int frow = l & 15, kgrp = (l>>4)*8;
  f32x4 acc[4][4] = {};

  for(int kt=0; kt<Kd; kt+=64){
    const unsigned short* Ap = A  + (size_t)(m0+sr)*Kd + kt + sc;
    const unsigned short* Bp = Bw + (size_t)(o0+sr)*Kd + kt + sc;
    __syncthreads();
    *(short8*)&Al[sr*72 + sc     ] = *(const short8*)(Ap);
    *(short8*)&Al[sr*72 + sc +  8] = *(const short8*)(Ap+8);
    *(short8*)&Al[sr*72 + sc + 16] = *(const short8*)(Ap+16);
    *(short8*)&Al[sr*72 + sc + 24] = *(const short8*)(Ap+24);
    *(short8*)&Bl[sr*72 + sc     ] = *(const short8*)(Bp);
    *(short8*)&Bl[sr*72 + sc +  8] = *(const short8*)(Bp+8);
    *(short8*)&Bl[sr*72 + sc + 16] = *(const short8*)(Bp+16);
    *(short8*)&Bl[sr*72 + sc + 24] = *(const short8*)(Bp+24);
    __syncthreads();
    #pragma unroll
    for(int ks=0; ks<2; ks++){
      short8 af[4], bf[4];
      #pragma unroll
      for(int f=0; f<4; f++){
        af[f] = *(const short8*)&Al[(wm+f*16+frow)*72 + ks*32 + kgrp];
        bf[f] = *(const short8*)&Bl[(wn+f*16+frow)*72 + ks*32 + kgrp];
      }
      #pragma unroll
      for(int i=0;i<4;i++)
        #pragma unroll
        for(int j=0;j<4;j++)
          acc[i][j] = __builtin_amdgcn_mfma_f32_16x16x32_bf16(af[i], bf[j], acc[i][j], 0,0,0);
    }
  }
  const int crow = (l>>4)*4, ccol = l & 15;
  #pragma unroll
  for(int i=0;i<4;i++){
    #pragma unroll
    for(int j=0;j<4;j++){
      int oc = o0 + wn + j*16 + ccol;
      float bv = bias[oc];
      #pragma unroll
      for(int r=0;r<4;r++){
        int mr = m0 + wm + i*16 + crow + r;
        Cout[(size_t)mr*O + oc] = acc[i][j][r] + bv;
      }
    }
  }
}

// ---------------- f32 -> bf16 convert ----------------
__global__ void wcvt_kernel(const float* __restrict__ in, unsigned short* __restrict__ out, int n){
  int i = blockIdx.x*blockDim.x + threadIdx.x;
  if(i < n) out[i] = f2bf(in[i]);
}

// ---------------- column stats over M rows ----------------
__global__ void colstats_kernel(const float* __restrict__ H, double* __restrict__ ssum,
                                double* __restrict__ ssq, int O){
  int o  = blockIdx.x*blockDim.x + threadIdx.x;
  int m0 = blockIdx.y*64;
  double s=0.0, s2=0.0;
  for(int m=m0;m<m0+64;m++){
    float h = H[(size_t)m*O + o];
    s += (double)h; s2 += (double)h*(double)h;
  }
  atomicAdd(&ssum[o], s); atomicAdd(&ssq[o], s2);
}

__global__ void bn_lrelu_bf16_kernel(const float* __restrict__ H, const float* __restrict__ scale,
                                     const float* __restrict__ shift, unsigned short* __restrict__ Hb,
                                     int O, long long total){
  long long i = (long long)blockIdx.x*blockDim.x + threadIdx.x;
  if(i >= total) return;
  int o = (int)(i % O);
  Hb[i] = f2bf(lrelu02(H[i]*scale[o] + shift[o]));
}

// ---------------- per-(b,o) max/min over n ----------------
__global__ void init_minmax_kernel(int* __restrict__ gmax, int* __restrict__ gmin, int n){
  int i = blockIdx.x*blockDim.x + threadIdx.x;
  if(i < n){ gmax[i] = -2147483647-1; gmin[i] = 2147483647; }
}

__global__ void colminmax_kernel(const float* __restrict__ H, int* __restrict__ gmax,
                                 int* __restrict__ gmin, int O){
  int o  = blockIdx.x*blockDim.x + threadIdx.x;
  int b  = blockIdx.y >> 4;
  int nt = blockIdx.y & 15;
  const float* Hp = H + (size_t)(b*NN + nt*256)*O + o;
  float mx = NEG_FLT, mn = POS_FLT;
  for(int i2=0;i2<256;i2++){
    float h = Hp[(size_t)i2*O];
    mx = fmaxf(mx, h); mn = fminf(mn, h);
  }
  atomicMax(&gmax[b*O + o], f2ord(mx));
  atomicMin(&gmin[b*O + o], f2ord(mn));
}

__global__ void t_apply_kernel(const int* __restrict__ gmax, const int* __restrict__ gmin,
                               const float* __restrict__ scale, const float* __restrict__ shift,
                               float* __restrict__ tfeat, int O){
  int i = blockIdx.x*blockDim.x + threadIdx.x;
  if(i >= BB*O) return;
  int o = i % O;
  float sc = scale[o];
  int ov = sc >= 0.f ? gmax[i] : gmin[i];
  float v = __int_as_float(ov >= 0 ? ov : (ov ^ 0x7fffffff));
  float y = v*sc + shift[o];
  tfeat[i] = fmaxf(y, 0.f);
}

// ---------------- FC + batch-BN(4) + relu ----------------
__global__ __launch_bounds__(128)
void fc_bn_relu_kernel(const float* __restrict__ X, const float* __restrict__ W,
                       const float* __restrict__ bias, const float* __restrict__ g,
                       const float* __restrict__ beta, float* __restrict__ Y,
                       int Cin, int Cout){
  int j = blockIdx.x;
  __shared__ float red[4][128];
  float a0=0,a1=0,a2=0,a3=0;
  const float* w = W + (size_t)j*Cin;
  for(int c=threadIdx.x;c<Cin;c+=128){
    float wv = w[c];
    a0 += X[c]*wv; a1 += X[Cin+c]*wv; a2 += X[2*Cin+c]*wv; a3 += X[3*Cin+c]*wv;
  }
  red[0][threadIdx.x]=a0; red[1][threadIdx.x]=a1; red[2][threadIdx.x]=a2; red[3][threadIdx.x]=a3;
  __syncthreads();
  for(int s=64;s>=1;s>>=1){
    if(threadIdx.x < s){
      #pragma unroll
      for(int b=0;b<4;b++) red[b][threadIdx.x] += red[b][threadIdx.x+s];
    }
    __syncthreads();
  }
  if(threadIdx.x == 0){
    float h[4];
    #pragma unroll
    for(int b=0;b<4;b++) h[b] = red[b][0] + bias[j];
    float m = 0.25f*(h[0]+h[1]+h[2]+h[3]);
    float var = 0.f;
    #pragma unroll
    for(int b=0;b<4;b++){ float d = h[b]-m; var += d*d; }
    var *= 0.25f;
    float sc = g[j]/sqrtf(var + 1e-5f);
    #pragma unroll
    for(int b=0;b<4;b++){
      float y = (h[b]-m)*sc + beta[j];
      Y[(size_t)b*Cout + j] = fmaxf(y, 0.f);
    }
  }
}

__global__ __launch_bounds__(64)
void fc3_kernel(const float* __restrict__ X, const float* __restrict__ W,
                const float* __restrict__ bias, float* __restrict__ out){
  int t = threadIdx.x; int b = t >> 4; int j = t & 15;
  float v;
  if(j < 12){
    float acc = 0.f;
    const float* w = W + (size_t)j*256;
    const float* xb = X + (size_t)b*256;
    for(int c=0;c<256;c++) acc += xb[c]*w[c];
    v = acc + bias[j];
    if(j==0 || j==5 || j==10) v += 1.f;
  } else {
    v = (j==15) ? 1.f : 0.f;
  }
  out[t] = v;
}

// ---------------- host-side kNN ----------------
template<int C>
static void run_knn(const float* xin, const float* xxb, float* distA, float* distB,
                    int* idxb, hipStream_t stream){
  if constexpr(C == 3){
    // fused: no dist materialization
    select3_kernel<<<BB*NN/4, 256, 0, stream>>>(xin, xxb, idxb);
  } else {
    for(int half=0; half<2; half++){
      int b0 = half*2;
      for(int j=0;j<2;j++){
        int b = b0 + j;
        float* dd = j==0 ? distA : distB;
        const float* xb = xin + (size_t)b*C*NN;
        const float* xx = xxb + (size_t)b*NN;
        dist_kernel<C><<<dim3(NN/128, NN/128), 256, 0, stream>>>(xb, xx, dd);
      }
      select_kernel<<<2*NN/4, 256, 0, stream>>>(distA, distB, idxb + (size_t)b0*NN*KK);
    }
  }
}

// ---------------- host-side edge block ----------------
template<int C, int O>
static void run_edge_block(const float* xin, const float* W, const float* bias,
                           const float* g, const float* e, float* xout, int catOff,
                           float* xxb, int* idxb, float* P, float* Q,
                           float* maxh, float* minh, float* distB,
                           float* Wt1, float* Wtd,
                           double* ssum, double* ssq,
                           float* scaleb, float* shiftb, unsigned short* catb, hipStream_t stream){
  xx_kernel<C><<<(BB*NN+255)/256, 256, 0, stream>>>(xin, xxb);
  run_knn<C>(xin, xxb, P /*distA = P..minh*/, distB, idxb, stream);
  if constexpr(C >= 32){
    wt_kernel<C,O><<<(C*O+255)/256, 256, 0, stream>>>(W, Wt1, Wtd);
    pq_gemm_kernel<C,O><<<dim3(BB*NN/64, O/64), 256, 0, stream>>>(xin, Wt1, Wtd, bias, P, Q);
  } else {
    pq_kernel<C,O><<<BB*NN/8, 256, 0, stream>>>(xin, W, bias, P, Q);
  }
  hipMemsetAsync(ssum, 0, O*sizeof(double), stream);
  hipMemsetAsync(ssq,  0, O*sizeof(double), stream);
  edge_reduce_kernel<O><<<BB*NN/8, O, 0, stream>>>(P, Q, idxb, maxh, minh, ssum, ssq);
  finalize_stats<<<(O+255)/256, 256, 0, stream>>>(ssum, ssq, g, e, scaleb, shiftb, O, (double)BB*NN*KK);
  edge_apply_kernel<O><<<(BB*NN*O+255)/256, 256, 0, stream>>>(maxh, minh, scaleb, shiftb, xout, catb, catOff);
}

extern "C" void kernel_launch(void* const* d_in, const int* in_sizes, int n_in,
                              void* d_out, int out_size, void* d_ws, size_t ws_size,
                              hipStream_t stream){
  (void)in_sizes; (void)n_in; (void)out_size; (void)ws_size;
  const float* x   = (const float*)d_in[0];
  const float* w1  = (const float*)d_in[1];  const float* b1 = (const float*)d_in[2];
  const float* g1  = (const float*)d_in[3];  const float* e1 = (const float*)d_in[4];
  const float* w2  = (const float*)d_in[5];  const float* b2 = (const float*)d_in[6];
  const float* g2  = (const float*)d_in[7];  const float* e2 = (const float*)d_in[8];
  const float* w3  = (const float*)d_in[9];  const float* b3 = (const float*)d_in[10];
  const float* g3  = (const float*)d_in[11]; const float* e3 = (const float*)d_in[12];
  const float* w4  = (const float*)d_in[13]; const float* b4 = (const float*)d_in[14];
  const float* g4  = (const float*)d_in[15]; const float* e4 = (const float*)d_in[16];
  const float* w5  = (const float*)d_in[17]; const float* b5 = (const float*)d_in[18];
  const float* g5  = (const float*)d_in[19]; const float* e5 = (const float*)d_in[20];
  const float* twp = (const float*)d_in[21]; const float* tbp = (const float*)d_in[22];
  const float* tg  = (const float*)d_in[23]; const float* te  = (const float*)d_in[24];
  const float* f1w = (const float*)d_in[25]; const float* f1b = (const float*)d_in[26];
  const float* f1g = (const float*)d_in[27]; const float* f1e = (const float*)d_in[28];
  const float* f2w = (const float*)d_in[29]; const float* f2b = (const float*)d_in[30];
  const float* f2g = (const float*)d_in[31]; const float* f2e = (const float*)d_in[32];
  const float* f3w = (const float*)d_in[33]; const float* f3b = (const float*)d_in[34];

  char* ws = (char*)d_ws;
  size_t off = 0;
  auto alloc = [&](size_t bytes)->void*{
    void* p = ws + off;
    off += (bytes + 255) & ~(size_t)255;
    return p;
  };
  int*    idxb  = (int*)   alloc((size_t)BB*NN*KK*4);
  float*  xxb   = (float*) alloc((size_t)BB*NN*4);
  float*  x1    = (float*) alloc((size_t)BB*64*NN*4);    // dead after block2 -> w5b
  float*  x2    = (float*) alloc((size_t)BB*64*NN*4);    // dead after block3 -> twb
  float*  x3    = (float*) alloc((size_t)BB*128*NN*4);
  float*  x4    = (float*) alloc((size_t)BB*256*NN*4);
  float*  P     = (float*) alloc((size_t)BB*NN*256*4);   // P..minh = distA (one batch, 64MB)
  float*  Q     = (float*) alloc((size_t)BB*NN*256*4);
  float*  maxh  = (float*) alloc((size_t)BB*NN*256*4);   // maxh+minh -> h5b after edge blocks
  float*  minh  = (float*) alloc((size_t)BB*NN*256*4);
  unsigned short* catb = (unsigned short*) alloc((size_t)BB*NN*512*2);
  float*  h5    = (float*) alloc((size_t)BB*NN*1024*4);  // distB during edge blocks; h5/h6 after
  float*  Wt1   = (float*) alloc((size_t)256*128*4);
  float*  Wtd   = (float*) alloc((size_t)256*128*4);
  double* ssum  = (double*)alloc(1024*8);
  double* ssq   = (double*)alloc(1024*8);
  float*  scaleb= (float*) alloc(1024*4);
  float*  shiftb= (float*) alloc(1024*4);
  int*    gmax  = (int*)   alloc((size_t)BB*1024*4);
  int*    gmin  = (int*)   alloc((size_t)BB*1024*4);
  float*  tfeat = (float*) alloc((size_t)BB*1024*4);
  float*  y1    = (float*) alloc((size_t)BB*512*4);
  float*  y2    = (float*) alloc((size_t)BB*256*4);

  unsigned short* w5b  = (unsigned short*)x1;
  unsigned short* twb  = (unsigned short*)x2;
  unsigned short* h5b  = (unsigned short*)maxh;
  float*          h6   = h5;

  run_edge_block<3,  64 >(x,  w1, b1, g1, e1, x1, 0,   xxb, idxb, P, Q, maxh, minh, h5, Wt1, Wtd, ssum, ssq, scaleb, shiftb, catb, stream);
  run_edge_block<64, 64 >(x1, w2, b2, g2, e2, x2, 64,  xxb, idxb, P, Q, maxh, minh, h5, Wt1, Wtd, ssum, ssq, scaleb, shiftb, catb, stream);
  run_edge_block<64, 128>(x2, w3, b3, g3, e3, x3, 128, xxb, idxb, P, Q, maxh, minh, h5, Wt1, Wtd, ssum, ssq, scaleb, shiftb, catb, stream);
  run_edge_block<128,256>(x3, w4, b4, g4, e4, x4, 256, xxb, idxb, P, Q, maxh, minh, h5, Wt1, Wtd, ssum, ssq, scaleb, shiftb, catb, stream);

  const int M = BB*NN; // 16384
  wcvt_kernel<<<(1024*512 +255)/256, 256, 0, stream>>>(w5,  w5b, 1024*512);
  wcvt_kernel<<<(1024*1024+255)/256, 256, 0, stream>>>(twp, twb, 1024*1024);

  gemm_bf16_kernel<<<dim3(M/128, 1024/128), 256, 0, stream>>>(catb, w5b, b5, h5, M, 512, 1024);
  hipMemsetAsync(ssum, 0, 1024*8, stream);
  hipMemsetAsync(ssq,  0, 1024*8, stream);
  colstats_kernel<<<dim3(1024/256, M/64), 256, 0, stream>>>(h5, ssum, ssq, 1024);
  finalize_stats<<<4, 256, 0, stream>>>(ssum, ssq, g5, e5, scaleb, shiftb, 1024, (double)M);
  bn_lrelu_bf16_kernel<<<(int)(((long long)M*1024+255)/256), 256, 0, stream>>>(h5, scaleb, shiftb, h5b, 1024, (long long)M*1024);

  gemm_bf16_kernel<<<dim3(M/128, 1024/128), 256, 0, stream>>>(h5b, twb, tbp, h6, M, 1024, 1024);
  hipMemsetAsync(ssum, 0, 1024*8, stream);
  hipMemsetAsync(ssq,  0, 1024*8, stream);
  init_minmax_kernel<<<(BB*1024+255)/256, 256, 0, stream>>>(gmax, gmin, BB*1024);
  colstats_kernel<<<dim3(1024/256, M/64), 256, 0, stream>>>(h6, ssum, ssq, 1024);
  colminmax_kernel<<<dim3(1024/256, BB*(NN/256)), 256, 0, stream>>>(h6, gmax, gmin, 1024);
  finalize_stats<<<4, 256, 0, stream>>>(ssum, ssq, tg, te, scaleb, shiftb, 1024, (double)M);
  t_apply_kernel<<<(BB*1024+255)/256, 256, 0, stream>>>(gmax, gmin, scaleb, shiftb, tfeat, 1024);

  fc_bn_relu_kernel<<<512, 128, 0, stream>>>(tfeat, f1w, f1b, f1g, f1e, y1, 1024, 512);
  fc_bn_relu_kernel<<<256, 128, 0, stream>>>(y1, f2w, f2b, f2g, f2e, y2, 512, 256);
  fc3_kernel<<<1, 64, 0, stream>>>(y2, f3w, f3b, (float*)d_out);
}

// Round 10
// 1827.507 us; speedup vs baseline: 1.0826x; 1.0326x over previous
//
#include <hip/hip_runtime.h>

#define BB 4
#define NN 4096
#define KK 40

#define NEG_FLT (-3.402823466e38f)
#define POS_FLT (3.402823466e38f)

typedef __attribute__((ext_vector_type(8))) short short8;
typedef __attribute__((ext_vector_type(4))) float f32x4;

__device__ __forceinline__ float lrelu02(float v){ return v > 0.f ? v : 0.2f*v; }
__device__ __forceinline__ int f2ord(float f){ int u = __float_as_int(f); return u >= 0 ? u : (u ^ 0x7fffffff); }
__device__ __forceinline__ unsigned ordu(float f){
  unsigned u = __float_as_uint(f);
  return (u & 0x80000000u) ? ~u : (u | 0x80000000u);
}
__device__ __forceinline__ unsigned long long packkey(float v, int m){
  return ((unsigned long long)ordu(v) << 32) | (unsigned)(~m);
}
__device__ __forceinline__ unsigned short f2bf(float f){   // RNE f32->bf16
  unsigned u = __float_as_uint(f);
  unsigned r = u + 0x7fffu + ((u>>16)&1u);
  return (unsigned short)(r>>16);
}

// ---------------- xx = sum_c x^2 ----------------
template<int C>
__global__ void xx_kernel(const float* __restrict__ x, float* __restrict__ xx){
  int i = blockIdx.x*blockDim.x + threadIdx.x;
  if(i >= BB*NN) return;
  int b = i / NN, n = i % NN;
  const float* xb = x + (size_t)b*C*NN + n;
  float s = 0.f;
  #pragma unroll
  for(int c=0;c<C;c++){ float v = xb[(size_t)c*NN]; s += v*v; }
  xx[i] = s;
}

// ---------------- distance matrix: 128x128 fp32 tile, K-step 16, SYMMETRIC ----------------
template<int C>
__global__ __launch_bounds__(256)
void dist_kernel(const float* __restrict__ xb, const float* __restrict__ xx,
                 float* __restrict__ dist){
  const int n0 = blockIdx.y*128, m0 = blockIdx.x*128;
  if(m0 < n0) return;
  __shared__ float As[16][132];
  __shared__ float Bs[16][132];
  const int tid = threadIdx.x;
  const int tx = tid & 15, ty = tid >> 4;
  const int lr = tid >> 4;           // staging k-row 0..15
  const int lc0 = (tid & 15)*8;      // staging col base
  float acc[8][8] = {};
  for(int kt=0; kt<C; kt+=16){
    __syncthreads();
    {
      const float* an = xb + (size_t)(kt+lr)*NN + n0 + lc0;
      const float* am = xb + (size_t)(kt+lr)*NN + m0 + lc0;
      *(float4*)&As[lr][lc0]   = *(const float4*)an;
      *(float4*)&As[lr][lc0+4] = *(const float4*)(an+4);
      *(float4*)&Bs[lr][lc0]   = *(const float4*)am;
      *(float4*)&Bs[lr][lc0+4] = *(const float4*)(am+4);
    }
    __syncthreads();
    #pragma unroll
    for(int cc=0;cc<16;cc++){
      float a[8], b[8];
      *(float4*)&a[0] = *(const float4*)&As[cc][ty*8];
      *(float4*)&a[4] = *(const float4*)&As[cc][ty*8+4];
      *(float4*)&b[0] = *(const float4*)&Bs[cc][tx*8];
      *(float4*)&b[4] = *(const float4*)&Bs[cc][tx*8+4];
      #pragma unroll
      for(int i=0;i<8;i++)
        #pragma unroll
        for(int j=0;j<8;j++) acc[i][j] += a[i]*b[j];
    }
  }
  float xmv[8], xnv[8];
  #pragma unroll
  for(int j=0;j<8;j++) xmv[j] = xx[m0 + tx*8 + j];
  #pragma unroll
  for(int i=0;i<8;i++) xnv[i] = xx[n0 + ty*8 + i];
  #pragma unroll
  for(int i=0;i<8;i++){
    int n = n0 + ty*8 + i;
    float xn = xnv[i];
    float4 r0, r1;
    r0.x = 2.f*acc[i][0] - xn - xmv[0];
    r0.y = 2.f*acc[i][1] - xn - xmv[1];
    r0.z = 2.f*acc[i][2] - xn - xmv[2];
    r0.w = 2.f*acc[i][3] - xn - xmv[3];
    r1.x = 2.f*acc[i][4] - xn - xmv[4];
    r1.y = 2.f*acc[i][5] - xn - xmv[5];
    r1.z = 2.f*acc[i][6] - xn - xmv[6];
    r1.w = 2.f*acc[i][7] - xn - xmv[7];
    *(float4*)(dist + (size_t)n*NN + m0 + tx*8)     = r0;
    *(float4*)(dist + (size_t)n*NN + m0 + tx*8 + 4) = r1;
  }
  if(m0 != n0){
    #pragma unroll
    for(int j=0;j<8;j++){
      int m = m0 + tx*8 + j;
      float xm = xmv[j];
      float4 r0, r1;
      r0.x = 2.f*acc[0][j] - xnv[0] - xm;
      r0.y = 2.f*acc[1][j] - xnv[1] - xm;
      r0.z = 2.f*acc[2][j] - xnv[2] - xm;
      r0.w = 2.f*acc[3][j] - xnv[3] - xm;
      r1.x = 2.f*acc[4][j] - xnv[4] - xm;
      r1.y = 2.f*acc[5][j] - xnv[5] - xm;
      r1.z = 2.f*acc[6][j] - xnv[6] - xm;
      r1.w = 2.f*acc[7][j] - xnv[7] - xm;
      *(float4*)(dist + (size_t)m*NN + n0 + ty*8)     = r0;
      *(float4*)(dist + (size_t)m*NN + n0 + ty*8 + 4) = r1;
    }
  }
}

// branch-free sorted-insert ladder on NAMED registers (no refs -> no scratch)
#define INSQ(vf, mi) do{ \
  unsigned long long _pk = packkey((vf),(mi)); \
  if(_pk > t7){ \
    unsigned long long _lo; \
    _lo = _pk < t0 ? _pk : t0;  t0 = _pk > t0 ? _pk : t0;  _pk = _lo; \
    _lo = _pk < t1 ? _pk : t1;  t1 = _pk > t1 ? _pk : t1;  _pk = _lo; \
    _lo = _pk < t2 ? _pk : t2;  t2 = _pk > t2 ? _pk : t2;  _pk = _lo; \
    _lo = _pk < t3 ? _pk : t3;  t3 = _pk > t3 ? _pk : t3;  _pk = _lo; \
    _lo = _pk < t4 ? _pk : t4;  t4 = _pk > t4 ? _pk : t4;  _pk = _lo; \
    _lo = _pk < t5 ? _pk : t5;  t5 = _pk > t5 ? _pk : t5;  _pk = _lo; \
    _lo = _pk < t6 ? _pk : t6;  t6 = _pk > t6 ? _pk : t6;  _pk = _lo; \
    t7 = _pk > t7 ? _pk : t7; \
  } \
}while(0)

// u32-value butterfly + ballot winner resolution; exact (value desc, index asc)
// top_k order: value max via 1-shuffle/step u32 butterfly; index tie (rare,
// needs two lanes' CURRENT heads exactly equal) -> u32 butterfly on ~index.
#define EXTRACT_MAX_M(mvar) do{ \
  unsigned _hi = (unsigned)(t0 >> 32); \
  unsigned _mx = _hi; \
  _Pragma("unroll") \
  for(int _off=32; _off; _off>>=1){ \
    unsigned _ov = __shfl_xor(_mx, _off, 64); \
    _mx = _ov > _mx ? _ov : _mx; \
  } \
  unsigned long long _cand = __ballot(_hi == _mx); \
  if(__popcll(_cand) == 1){ \
    int _wl = (int)(__ffsll((long long)_cand) - 1); \
    unsigned _lo = (unsigned)__shfl((int)(unsigned)t0, _wl, 64); \
    (mvar) = (int)(~_lo); \
  } else { \
    unsigned _bi = (_hi == _mx) ? (unsigned)t0 : 0u; \
    _Pragma("unroll") \
    for(int _off=32; _off; _off>>=1){ \
      unsigned _ov = __shfl_xor(_bi, _off, 64); \
      _bi = _ov > _bi ? _ov : _bi; \
    } \
    (mvar) = (int)(~_bi); \
  } \
}while(0)

// ---------------- top-K over materialized dist rows (C>=64 path) ----------------
__global__ __launch_bounds__(256)
void select_kernel(const float* __restrict__ dA, const float* __restrict__ dB,
                   int* __restrict__ idx){
  const int wid = threadIdx.x >> 6;
  const int lane = threadIdx.x & 63;
  const int r = blockIdx.x*4 + wid;            // 0..8191 (two batches)
  const float* row = (r < NN) ? (dA + (size_t)r*NN) : (dB + (size_t)(r-NN)*NN);

  unsigned long long t0=0,t1=0,t2=0,t3=0,t4=0,t5=0,t6=0,t7=0;
  unsigned long long done = 0ull;

  #pragma unroll 4
  for(int j=0;j<16;j++){
    float4 v = *(const float4*)(row + j*256 + lane*4);
    int mb = j*256 + lane*4;
    INSQ(v.x, mb+0); INSQ(v.y, mb+1); INSQ(v.z, mb+2); INSQ(v.w, mb+3);
  }

  __shared__ int outbuf[4][KK];
  #pragma unroll 1
  for(int k=0;k<KK;k++){
    int m;
    EXTRACT_MAX_M(m);
    if(lane == ((m>>2)&63)){
      done |= 1ull << (((m>>8)<<2) | (m&3));
      t0=t1;t1=t2;t2=t3;t3=t4;t4=t5;t5=t6;t6=t7;t7=0;
      if(t0 == 0ull){
        #pragma unroll 1
        for(int j=0;j<16;j++){
          float4 v = *(const float4*)(row + j*256 + lane*4);
          int mb = j*256 + lane*4;
          if(!((done>>(j*4+0))&1)) INSQ(v.x, mb+0);
          if(!((done>>(j*4+1))&1)) INSQ(v.y, mb+1);
          if(!((done>>(j*4+2))&1)) INSQ(v.z, mb+2);
          if(!((done>>(j*4+3))&1)) INSQ(v.w, mb+3);
        }
      }
    }
    if(lane == 0) outbuf[wid][k] = m;
  }
  if(lane < KK) idx[(size_t)r*KK + lane] = outbuf[wid][lane];
}

// ---------------- fused C=3 kNN: distances on the fly, no dist buffer ----------------
__global__ __launch_bounds__(256)
void select3_kernel(const float* __restrict__ x, const float* __restrict__ xx,
                    int* __restrict__ idx){
  const int wid = threadIdx.x >> 6;
  const int lane = threadIdx.x & 63;
  const int r = blockIdx.x*4 + wid;            // 0..BB*NN-1
  const int b = r / NN, n = r % NN;
  const float* xb  = x + (size_t)b*3*NN;
  const float* xxb = xx + (size_t)b*NN;
  const float c0 = xb[n], c1 = xb[NN+n], c2 = xb[2*NN+n];
  const float xn = xxb[n];

  unsigned long long t0=0,t1=0,t2=0,t3=0,t4=0,t5=0,t6=0,t7=0;
  unsigned long long done = 0ull;

  #pragma unroll 4
  for(int j=0;j<16;j++){
    int mb = j*256 + lane*4;
    float4 a  = *(const float4*)(xb + mb);
    float4 bb = *(const float4*)(xb + NN + mb);
    float4 c  = *(const float4*)(xb + 2*NN + mb);
    float4 xm = *(const float4*)(xxb + mb);
    float vx, vy, vz, vw;
    { float s = c0*a.x; s += c1*bb.x; s += c2*c.x; vx = 2.f*s - xn - xm.x; }
    { float s = c0*a.y; s += c1*bb.y; s += c2*c.y; vy = 2.f*s - xn - xm.y; }
    { float s = c0*a.z; s += c1*bb.z; s += c2*c.z; vz = 2.f*s - xn - xm.z; }
    { float s = c0*a.w; s += c1*bb.w; s += c2*c.w; vw = 2.f*s - xn - xm.w; }
    INSQ(vx, mb+0); INSQ(vy, mb+1); INSQ(vz, mb+2); INSQ(vw, mb+3);
  }

  __shared__ int outbuf[4][KK];
  #pragma unroll 1
  for(int k=0;k<KK;k++){
    int m;
    EXTRACT_MAX_M(m);
    if(lane == ((m>>2)&63)){
      done |= 1ull << (((m>>8)<<2) | (m&3));
      t0=t1;t1=t2;t2=t3;t3=t4;t4=t5;t5=t6;t6=t7;t7=0;
      if(t0 == 0ull){
        // rare rebuild: recompute distances, skipping extracted
        #pragma unroll 1
        for(int j=0;j<16;j++){
          int mb = j*256 + lane*4;
          float4 a  = *(const float4*)(xb + mb);
          float4 bb = *(const float4*)(xb + NN + mb);
          float4 c  = *(const float4*)(xb + 2*NN + mb);
          float4 xm = *(const float4*)(xxb + mb);
          float vx, vy, vz, vw;
          { float s = c0*a.x; s += c1*bb.x; s += c2*c.x; vx = 2.f*s - xn - xm.x; }
          { float s = c0*a.y; s += c1*bb.y; s += c2*c.y; vy = 2.f*s - xn - xm.y; }
          { float s = c0*a.z; s += c1*bb.z; s += c2*c.z; vz = 2.f*s - xn - xm.z; }
          { float s = c0*a.w; s += c1*bb.w; s += c2*c.w; vw = 2.f*s - xn - xm.w; }
          if(!((done>>(j*4+0))&1)) INSQ(vx, mb+0);
          if(!((done>>(j*4+1))&1)) INSQ(vy, mb+1);
          if(!((done>>(j*4+2))&1)) INSQ(vz, mb+2);
          if(!((done>>(j*4+3))&1)) INSQ(vw, mb+3);
        }
      }
    }
    if(lane == 0) outbuf[wid][k] = m;
  }
  if(lane < KK) idx[(size_t)r*KK + lane] = outbuf[wid][lane];
}

// ---------------- W transpose + delta ----------------
template<int C, int O>
__global__ void wt_kernel(const float* __restrict__ w, float* __restrict__ Wt1,
                          float* __restrict__ Wtd){
  int i = blockIdx.x*256 + threadIdx.x;
  if(i >= C*O) return;
  int c = i / O, o = i % O;
  float a = w[(size_t)o*2*C + c];
  float b = w[(size_t)o*2*C + C + c];
  Wt1[i] = a; Wtd[i] = b - a;
}

// ---------------- pq as dual-output fp32 GEMM ----------------
template<int C, int O>
__global__ __launch_bounds__(256)
void pq_gemm_kernel(const float* __restrict__ x, const float* __restrict__ Wt1,
                    const float* __restrict__ Wtd, const float* __restrict__ bias,
                    float* __restrict__ P, float* __restrict__ Q){
  __shared__ float Xs[32][68];
  __shared__ float W1s[32][68];
  __shared__ float Wds[32][68];
  const int t0 = blockIdx.x*64;
  const int o0 = blockIdx.y*64;
  const int b  = t0 / NN, n0 = t0 % NN;
  const float* xb = x + (size_t)b*C*NN;
  const int tid = threadIdx.x;
  const int tx = tid & 15, ty = tid >> 4;
  const int lr = tid >> 3, lc0 = (tid & 7)*8;
  float pa[4][4] = {}, qa[4][4] = {};
  for(int kt=0; kt<C; kt+=32){
    __syncthreads();
    {
      const float* xs = xb + (size_t)(kt+lr)*NN + n0 + lc0;
      *(float4*)&Xs[lr][lc0]   = *(const float4*)xs;
      *(float4*)&Xs[lr][lc0+4] = *(const float4*)(xs+4);
      const float* w1 = Wt1 + (size_t)(kt+lr)*O + o0 + lc0;
      *(float4*)&W1s[lr][lc0]   = *(const float4*)w1;
      *(float4*)&W1s[lr][lc0+4] = *(const float4*)(w1+4);
      const float* wd = Wtd + (size_t)(kt+lr)*O + o0 + lc0;
      *(float4*)&Wds[lr][lc0]   = *(const float4*)wd;
      *(float4*)&Wds[lr][lc0+4] = *(const float4*)(wd+4);
    }
    __syncthreads();
    #pragma unroll
    for(int cc=0;cc<32;cc++){
      float a[4], w[4], d[4];
      *(float4*)a = *(const float4*)&Xs[cc][ty*4];
      *(float4*)w = *(const float4*)&W1s[cc][tx*4];
      *(float4*)d = *(const float4*)&Wds[cc][tx*4];
      #pragma unroll
      for(int i=0;i<4;i++)
        #pragma unroll
        for(int j=0;j<4;j++){
          pa[i][j] += a[i]*w[j];
          qa[i][j] += a[i]*d[j];
        }
    }
  }
  #pragma unroll
  for(int i=0;i<4;i++){
    size_t t = (size_t)t0 + ty*4 + i;
    #pragma unroll
    for(int j=0;j<4;j++){
      int o = o0 + tx*4 + j;
      P[t*O + o] = pa[i][j];
      Q[t*O + o] = qa[i][j] + bias[o];
    }
  }
}

// ---------------- P/Q for C=3 (cheap scalar path) ----------------
template<int C, int O>
__global__ __launch_bounds__(256)
void pq_kernel(const float* __restrict__ x, const float* __restrict__ W,
               const float* __restrict__ bias,
               float* __restrict__ P, float* __restrict__ Q){
  constexpr int G = 256/O;
  constexpr int T = 8/G;
  constexpr int CP = ((C+3)/4)*4;
  __shared__ float xs[8][CP];
  const int tid = threadIdx.x;
  const long long t0b = (long long)blockIdx.x*8;
  const int b = (int)(t0b / NN), n0 = (int)(t0b % NN);
  const float* xb = x + (size_t)b*C*NN;
  for(int e=tid; e<8*C; e+=256){
    int tt = e / C, c = e % C;
    xs[tt][c] = xb[(size_t)c*NN + n0 + tt];
  }
  __syncthreads();

  const int o = tid % O, g = tid / O;
  const float* wrow = W + (size_t)o*2*C;
  float p[T], q[T];
  #pragma unroll
  for(int jt=0;jt<T;jt++){ p[jt]=0.f; q[jt]=0.f; }

  float w0=wrow[0], w1v=wrow[1], w2v=wrow[2];
  float d0=wrow[C+0]-w0, d1=wrow[C+1]-w1v, d2=wrow[C+2]-w2v;
  #pragma unroll
  for(int jt=0;jt<T;jt++){
    float a0=xs[g*T+jt][0], a1=xs[g*T+jt][1], a2=xs[g*T+jt][2];
    p[jt] += w0*a0; p[jt] += w1v*a1; p[jt] += w2v*a2;
    q[jt] += d0*a0; q[jt] += d1*a1; q[jt] += d2*a2;
  }
  float bv = bias[o];
  #pragma unroll
  for(int jt=0;jt<T;jt++){
    size_t t = (size_t)t0b + g*T + jt;
    P[t*O + o] = p[jt];
    Q[t*O + o] = q[jt] + bv;
  }
}

// ---------------- edge reduce (single pass, O threads) ----------------
template<int O>
__global__ void edge_reduce_kernel(const float* __restrict__ P, const float* __restrict__ Q,
                                   const int* __restrict__ idx,
                                   float* __restrict__ maxh, float* __restrict__ minh,
                                   double* __restrict__ ssum, double* __restrict__ ssq){
  const int o = threadIdx.x;
  const int TN = 8;
  int t0 = blockIdx.x*TN;
  double s = 0.0, s2 = 0.0;
  for(int t=t0;t<t0+TN;t++){
    int bbase = (t/NN)*NN;
    float q = Q[(size_t)t*O + o];
    const int* id = idx + (size_t)t*KK;
    float mx = NEG_FLT, mn = POS_FLT;
    for(int k=0;k<KK;k++){
      int m = id[k];
      float h = P[(size_t)(bbase+m)*O + o] + q;
      mx = fmaxf(mx, h); mn = fminf(mn, h);
      s += (double)h; s2 += (double)h*(double)h;
    }
    maxh[(size_t)t*O + o] = mx;
    minh[(size_t)t*O + o] = mn;
  }
  atomicAdd(&ssum[o], s);
  atomicAdd(&ssq[o], s2);
}

// ---------------- BN stat finalize ----------------
__global__ void finalize_stats(const double* __restrict__ ssum, const double* __restrict__ ssq,
                               const float* __restrict__ g, const float* __restrict__ beta,
                               float* __restrict__ scale, float* __restrict__ shift,
                               int O, double cnt){
  int o = blockIdx.x*blockDim.x + threadIdx.x;
  if(o >= O) return;
  double m = ssum[o]/cnt;
  double v = ssq[o]/cnt - m*m;
  if(v < 0.0) v = 0.0;
  float sc = g[o]/sqrtf((float)v + 1e-5f);
  scale[o] = sc;
  shift[o] = beta[o] - (float)m*sc;
}

// ---------------- edge apply ----------------
template<int O>
__global__ void edge_apply_kernel(const float* __restrict__ maxh, const float* __restrict__ minh,
                                  const float* __restrict__ scale, const float* __restrict__ shift,
                                  float* __restrict__ xout, unsigned short* __restrict__ cat,
                                  int catOff){
  int i = blockIdx.x*blockDim.x + threadIdx.x;
  if(i >= BB*NN*O) return;
  int o = i % O; int t = i / O; int n = t % NN; int b = t / NN;
  float sc = scale[o];
  float v = sc >= 0.f ? maxh[i] : minh[i];
  float y = lrelu02(v*sc + shift[o]);
  xout[((size_t)b*O + o)*NN + n] = y;
  cat[(size_t)t*512 + catOff + o] = f2bf(y);
}

// ---------------- bf16 MFMA GEMM ----------------
__global__ __launch_bounds__(256)
void gemm_bf16_kernel(const unsigned short* __restrict__ A, const unsigned short* __restrict__ Bw,
                      const float* __restrict__ bias, float* __restrict__ Cout,
                      int M, int Kd, int O){
  __shared__ unsigned short Al[128*72];
  __shared__ unsigned short Bl[128*72];
  const int m0 = blockIdx.x*128, o0 = blockIdx.y*128;
  const int tid = threadIdx.x;
  const int w = tid >> 6, l = tid & 63;
  const int wm = (w>>1)*64, wn = (w&1)*64;
  const int sr = tid >> 1;
  const int sc = (tid & 1)*32;
  const int frow = l & 15, kgrp = (l>>4)*8;
  f32x4 acc[4][4] = {};

  for(int kt=0; kt<Kd; kt+=64){
    const unsigned short* Ap = A  + (size_t)(m0+sr)*Kd + kt + sc;
    const unsigned short* Bp = Bw + (size_t)(o0+sr)*Kd + kt + sc;
    __syncthreads();
    *(short8*)&Al[sr*72 + sc     ] = *(const short8*)(Ap);
    *(short8*)&Al[sr*72 + sc +  8] = *(const short8*)(Ap+8);
    *(short8*)&Al[sr*72 + sc + 16] = *(const short8*)(Ap+16);
    *(short8*)&Al[sr*72 + sc + 24] = *(const short8*)(Ap+24);
    *(short8*)&Bl[sr*72 + sc     ] = *(const short8*)(Bp);
    *(short8*)&Bl[sr*72 + sc +  8] = *(const short8*)(Bp+8);
    *(short8*)&Bl[sr*72 + sc + 16] = *(const short8*)(Bp+16);
    *(short8*)&Bl[sr*72 + sc + 24] = *(const short8*)(Bp+24);
    __syncthreads();
    #pragma unroll
    for(int ks=0; ks<2; ks++){
      short8 af[4], bf[4];
      #pragma unroll
      for(int f=0; f<4; f++){
        af[f] = *(const short8*)&Al[(wm+f*16+frow)*72 + ks*32 + kgrp];
        bf[f] = *(const short8*)&Bl[(wn+f*16+frow)*72 + ks*32 + kgrp];
      }
      #pragma unroll
      for(int i=0;i<4;i++)
        #pragma unroll
        for(int j=0;j<4;j++)
          acc[i][j] = __builtin_amdgcn_mfma_f32_16x16x32_bf16(af[i], bf[j], acc[i][j], 0,0,0);
    }
  }
  const int crow = (l>>4)*4, ccol = l & 15;
  #pragma unroll
  for(int i=0;i<4;i++){
    #pragma unroll
    for(int j=0;j<4;j++){
      int oc = o0 + wn + j*16 + ccol;
      float bv = bias[oc];
      #pragma unroll
      for(int r=0;r<4;r++){
        int mr = m0 + wm + i*16 + crow + r;
        Cout[(size_t)mr*O + oc] = acc[i][j][r] + bv;
      }
    }
  }
}

// ---------------- f32 -> bf16 convert ----------------
__global__ void wcvt_kernel(const float* __restrict__ in, unsigned short* __restrict__ out, int n){
  int i = blockIdx.x*blockDim.x + threadIdx.x;
  if(i < n) out[i] = f2bf(in[i]);
}

// ---------------- column stats over M rows ----------------
__global__ void colstats_kernel(const float* __restrict__ H, double* __restrict__ ssum,
                                double* __restrict__ ssq, int O){
  int o  = blockIdx.x*blockDim.x + threadIdx.x;
  int m0 = blockIdx.y*64;
  double s=0.0, s2=0.0;
  for(int m=m0;m<m0+64;m++){
    float h = H[(size_t)m*O + o];
    s += (double)h; s2 += (double)h*(double)h;
  }
  atomicAdd(&ssum[o], s); atomicAdd(&ssq[o], s2);
}

__global__ void bn_lrelu_bf16_kernel(const float* __restrict__ H, const float* __restrict__ scale,
                                     const float* __restrict__ shift, unsigned short* __restrict__ Hb,
                                     int O, long long total){
  long long i = (long long)blockIdx.x*blockDim.x + threadIdx.x;
  if(i >= total) return;
  int o = (int)(i % O);
  Hb[i] = f2bf(lrelu02(H[i]*scale[o] + shift[o]));
}

// ---------------- per-(b,o) max/min over n ----------------
__global__ void init_minmax_kernel(int* __restrict__ gmax, int* __restrict__ gmin, int n){
  int i = blockIdx.x*blockDim.x + threadIdx.x;
  if(i < n){ gmax[i] = -2147483647-1; gmin[i] = 2147483647; }
}

__global__ void colminmax_kernel(const float* __restrict__ H, int* __restrict__ gmax,
                                 int* __restrict__ gmin, int O){
  int o  = blockIdx.x*blockDim.x + threadIdx.x;
  int b  = blockIdx.y >> 4;
  int nt = blockIdx.y & 15;
  const float* Hp = H + (size_t)(b*NN + nt*256)*O + o;
  float mx = NEG_FLT, mn = POS_FLT;
  for(int i2=0;i2<256;i2++){
    float h = Hp[(size_t)i2*O];
    mx = fmaxf(mx, h); mn = fminf(mn, h);
  }
  atomicMax(&gmax[b*O + o], f2ord(mx));
  atomicMin(&gmin[b*O + o], f2ord(mn));
}

__global__ void t_apply_kernel(const int* __restrict__ gmax, const int* __restrict__ gmin,
                               const float* __restrict__ scale, const float* __restrict__ shift,
                               float* __restrict__ tfeat, int O){
  int i = blockIdx.x*blockDim.x + threadIdx.x;
  if(i >= BB*O) return;
  int o = i % O;
  float sc = scale[o];
  int ov = sc >= 0.f ? gmax[i] : gmin[i];
  float v = __int_as_float(ov >= 0 ? ov : (ov ^ 0x7fffffff));
  float y = v*sc + shift[o];
  tfeat[i] = fmaxf(y, 0.f);
}

// ---------------- FC + batch-BN(4) + relu ----------------
__global__ __launch_bounds__(128)
void fc_bn_relu_kernel(const float* __restrict__ X, const float* __restrict__ W,
                       const float* __restrict__ bias, const float* __restrict__ g,
                       const float* __restrict__ beta, float* __restrict__ Y,
                       int Cin, int Cout){
  int j = blockIdx.x;
  __shared__ float red[4][128];
  float a0=0,a1=0,a2=0,a3=0;
  const float* w = W + (size_t)j*Cin;
  for(int c=threadIdx.x;c<Cin;c+=128){
    float wv = w[c];
    a0 += X[c]*wv; a1 += X[Cin+c]*wv; a2 += X[2*Cin+c]*wv; a3 += X[3*Cin+c]*wv;
  }
  red[0][threadIdx.x]=a0; red[1][threadIdx.x]=a1; red[2][threadIdx.x]=a2; red[3][threadIdx.x]=a3;
  __syncthreads();
  for(int s=64;s>=1;s>>=1){
    if(threadIdx.x < s){
      #pragma unroll
      for(int b=0;b<4;b++) red[b][threadIdx.x] += red[b][threadIdx.x+s];
    }
    __syncthreads();
  }
  if(threadIdx.x == 0){
    float h[4];
    #pragma unroll
    for(int b=0;b<4;b++) h[b] = red[b][0] + bias[j];
    float m = 0.25f*(h[0]+h[1]+h[2]+h[3]);
    float var = 0.f;
    #pragma unroll
    for(int b=0;b<4;b++){ float d = h[b]-m; var += d*d; }
    var *= 0.25f;
    float sc = g[j]/sqrtf(var + 1e-5f);
    #pragma unroll
    for(int b=0;b<4;b++){
      float y = (h[b]-m)*sc + beta[j];
      Y[(size_t)b*Cout + j] = fmaxf(y, 0.f);
    }
  }
}

__global__ __launch_bounds__(64)
void fc3_kernel(const float* __restrict__ X, const float* __restrict__ W,
                const float* __restrict__ bias, float* __restrict__ out){
  int t = threadIdx.x; int b = t >> 4; int j = t & 15;
  float v;
  if(j < 12){
    float acc = 0.f;
    const float* w = W + (size_t)j*256;
    const float* xb = X + (size_t)b*256;
    for(int c=0;c<256;c++) acc += xb[c]*w[c];
    v = acc + bias[j];
    if(j==0 || j==5 || j==10) v += 1.f;
  } else {
    v = (j==15) ? 1.f : 0.f;
  }
  out[t] = v;
}

// ---------------- host-side kNN ----------------
template<int C>
static void run_knn(const float* xin, const float* xxb, float* distA, float* distB,
                    int* idxb, hipStream_t stream){
  if constexpr(C == 3){
    select3_kernel<<<BB*NN/4, 256, 0, stream>>>(xin, xxb, idxb);
  } else {
    for(int half=0; half<2; half++){
      int b0 = half*2;
      for(int j=0;j<2;j++){
        int b = b0 + j;
        float* dd = j==0 ? distA : distB;
        const float* xb = xin + (size_t)b*C*NN;
        const float* xx = xxb + (size_t)b*NN;
        dist_kernel<C><<<dim3(NN/128, NN/128), 256, 0, stream>>>(xb, xx, dd);
      }
      select_kernel<<<2*NN/4, 256, 0, stream>>>(distA, distB, idxb + (size_t)b0*NN*KK);
    }
  }
}

// ---------------- host-side edge block ----------------
template<int C, int O>
static void run_edge_block(const float* xin, const float* W, const float* bias,
                           const float* g, const float* e, float* xout, int catOff,
                           float* xxb, int* idxb, float* P, float* Q,
                           float* maxh, float* minh, float* distB,
                           float* Wt1, float* Wtd,
                           double* ssum, double* ssq,
                           float* scaleb, float* shiftb, unsigned short* catb, hipStream_t stream){
  xx_kernel<C><<<(BB*NN+255)/256, 256, 0, stream>>>(xin, xxb);
  run_knn<C>(xin, xxb, P /*distA = P..minh*/, distB, idxb, stream);
  if constexpr(C >= 32){
    wt_kernel<C,O><<<(C*O+255)/256, 256, 0, stream>>>(W, Wt1, Wtd);
    pq_gemm_kernel<C,O><<<dim3(BB*NN/64, O/64), 256, 0, stream>>>(xin, Wt1, Wtd, bias, P, Q);
  } else {
    pq_kernel<C,O><<<BB*NN/8, 256, 0, stream>>>(xin, W, bias, P, Q);
  }
  hipMemsetAsync(ssum, 0, O*sizeof(double), stream);
  hipMemsetAsync(ssq,  0, O*sizeof(double), stream);
  edge_reduce_kernel<O><<<BB*NN/8, O, 0, stream>>>(P, Q, idxb, maxh, minh, ssum, ssq);
  finalize_stats<<<(O+255)/256, 256, 0, stream>>>(ssum, ssq, g, e, scaleb, shiftb, O, (double)BB*NN*KK);
  edge_apply_kernel<O><<<(BB*NN*O+255)/256, 256, 0, stream>>>(maxh, minh, scaleb, shiftb, xout, catb, catOff);
}

extern "C" void kernel_launch(void* const* d_in, const int* in_sizes, int n_in,
                              void* d_out, int out_size, void* d_ws, size_t ws_size,
                              hipStream_t stream){
  (void)in_sizes; (void)n_in; (void)out_size; (void)ws_size;
  const float* x   = (const float*)d_in[0];
  const float* w1  = (const float*)d_in[1];  const float* b1 = (const float*)d_in[2];
  const float* g1  = (const float*)d_in[3];  const float* e1 = (const float*)d_in[4];
  const float* w2  = (const float*)d_in[5];  const float* b2 = (const float*)d_in[6];
  const float* g2  = (const float*)d_in[7];  const float* e2 = (const float*)d_in[8];
  const float* w3  = (const float*)d_in[9];  const float* b3 = (const float*)d_in[10];
  const float* g3  = (const float*)d_in[11]; const float* e3 = (const float*)d_in[12];
  const float* w4  = (const float*)d_in[13]; const float* b4 = (const float*)d_in[14];
  const float* g4  = (const float*)d_in[15]; const float* e4 = (const float*)d_in[16];
  const float* w5  = (const float*)d_in[17]; const float* b5 = (const float*)d_in[18];
  const float* g5  = (const float*)d_in[19]; const float* e5 = (const float*)d_in[20];
  const float* twp = (const float*)d_in[21]; const float* tbp = (const float*)d_in[22];
  const float* tg  = (const float*)d_in[23]; const float* te  = (const float*)d_in[24];
  const float* f1w = (const float*)d_in[25]; const float* f1b = (const float*)d_in[26];
  const float* f1g = (const float*)d_in[27]; const float* f1e = (const float*)d_in[28];
  const float* f2w = (const float*)d_in[29]; const float* f2b = (const float*)d_in[30];
  const float* f2g = (const float*)d_in[31]; const float* f2e = (const float*)d_in[32];
  const float* f3w = (const float*)d_in[33]; const float* f3b = (const float*)d_in[34];

  char* ws = (char*)d_ws;
  size_t off = 0;
  auto alloc = [&](size_t bytes)->void*{
    void* p = ws + off;
    off += (bytes + 255) & ~(size_t)255;
    return p;
  };
  int*    idxb  = (int*)   alloc((size_t)BB*NN*KK*4);
  float*  xxb   = (float*) alloc((size_t)BB*NN*4);
  float*  x1    = (float*) alloc((size_t)BB*64*NN*4);    // dead after block2 -> w5b
  float*  x2    = (float*) alloc((size_t)BB*64*NN*4);    // dead after block3 -> twb
  float*  x3    = (float*) alloc((size_t)BB*128*NN*4);
  float*  x4    = (float*) alloc((size_t)BB*256*NN*4);
  float*  P     = (float*) alloc((size_t)BB*NN*256*4);   // P..minh = distA (one batch, 64MB)
  float*  Q     = (float*) alloc((size_t)BB*NN*256*4);
  float*  maxh  = (float*) alloc((size_t)BB*NN*256*4);   // maxh+minh -> h5b after edge blocks
  float*  minh  = (float*) alloc((size_t)BB*NN*256*4);
  unsigned short* catb = (unsigned short*) alloc((size_t)BB*NN*512*2);
  float*  h5    = (float*) alloc((size_t)BB*NN*1024*4);  // distB during edge blocks; h5/h6 after
  float*  Wt1   = (float*) alloc((size_t)256*128*4);
  float*  Wtd   = (float*) alloc((size_t)256*128*4);
  double* ssum  = (double*)alloc(1024*8);
  double* ssq   = (double*)alloc(1024*8);
  float*  scaleb= (float*) alloc(1024*4);
  float*  shiftb= (float*) alloc(1024*4);
  int*    gmax  = (int*)   alloc((size_t)BB*1024*4);
  int*    gmin  = (int*)   alloc((size_t)BB*1024*4);
  float*  tfeat = (float*) alloc((size_t)BB*1024*4);
  float*  y1    = (float*) alloc((size_t)BB*512*4);
  float*  y2    = (float*) alloc((size_t)BB*256*4);

  unsigned short* w5b  = (unsigned short*)x1;
  unsigned short* twb  = (unsigned short*)x2;
  unsigned short* h5b  = (unsigned short*)maxh;
  float*          h6   = h5;

  run_edge_block<3,  64 >(x,  w1, b1, g1, e1, x1, 0,   xxb, idxb, P, Q, maxh, minh, h5, Wt1, Wtd, ssum, ssq, scaleb, shiftb, catb, stream);
  run_edge_block<64, 64 >(x1, w2, b2, g2, e2, x2, 64,  xxb, idxb, P, Q, maxh, minh, h5, Wt1, Wtd, ssum, ssq, scaleb, shiftb, catb, stream);
  run_edge_block<64, 128>(x2, w3, b3, g3, e3, x3, 128, xxb, idxb, P, Q, maxh, minh, h5, Wt1, Wtd, ssum, ssq, scaleb, shiftb, catb, stream);
  run_edge_block<128,256>(x3, w4, b4, g4, e4, x4, 256, xxb, idxb, P, Q, maxh, minh, h5, Wt1, Wtd, ssum, ssq, scaleb, shiftb, catb, stream);

  const int M = BB*NN; // 16384
  wcvt_kernel<<<(1024*512 +255)/256, 256, 0, stream>>>(w5,  w5b, 1024*512);
  wcvt_kernel<<<(1024*1024+255)/256, 256, 0, stream>>>(twp, twb, 1024*1024);

  gemm_bf16_kernel<<<dim3(M/128, 1024/128), 256, 0, stream>>>(catb, w5b, b5, h5, M, 512, 1024);
  hipMemsetAsync(ssum, 0, 1024*8, stream);
  hipMemsetAsync(ssq,  0, 1024*8, stream);
  colstats_kernel<<<dim3(1024/256, M/64), 256, 0, stream>>>(h5, ssum, ssq, 1024);
  finalize_stats<<<4, 256, 0, stream>>>(ssum, ssq, g5, e5, scaleb, shiftb, 1024, (double)M);
  bn_lrelu_bf16_kernel<<<(int)(((long long)M*1024+255)/256), 256, 0, stream>>>(h5, scaleb, shiftb, h5b, 1024, (long long)M*1024);

  gemm_bf16_kernel<<<dim3(M/128, 1024/128), 256, 0, stream>>>(h5b, twb, tbp, h6, M, 1024, 1024);
  hipMemsetAsync(ssum, 0, 1024*8, stream);
  hipMemsetAsync(ssq,  0, 1024*8, stream);
  init_minmax_kernel<<<(BB*1024+255)/256, 256, 0, stream>>>(gmax, gmin, BB*1024);
  colstats_kernel<<<dim3(1024/256, M/64), 256, 0, stream>>>(h6, ssum, ssq, 1024);
  colminmax_kernel<<<dim3(1024/256, BB*(NN/256)), 256, 0, stream>>>(h6, gmax, gmin, 1024);
  finalize_stats<<<4, 256, 0, stream>>>(ssum, ssq, tg, te, scaleb, shiftb, 1024, (double)M);
  t_apply_kernel<<<(BB*1024+255)/256, 256, 0, stream>>>(gmax, gmin, scaleb, shiftb, tfeat, 1024);

  fc_bn_relu_kernel<<<512, 128, 0, stream>>>(tfeat, f1w, f1b, f1g, f1e, y1, 1024, 512);
  fc_bn_relu_kernel<<<256, 128, 0, stream>>>(y1, f2w, f2b, f2g, f2e, y2, 512, 256);
  fc3_kernel<<<1, 64, 0, stream>>>(y2, f3w, f3b, (float*)d_out);
}